// Round 1
// baseline (611.380 us; speedup 1.0000x reference)
//
#include <hip/hip_runtime.h>
#include <cstdint>

#define DM    768
#define DI    1536
#define PP    64
#define HH    24
#define NN    64
#define CONVD 1664
#define DINP  3224
#define NP1   3328   // 3224 padded to 26*128
#define LL    1024
#define ROWS  2048   // BATCH*LL
#define EPSF  1e-5f

typedef unsigned short ushortT;
typedef __attribute__((ext_vector_type(8))) __bf16 bf16x8;
typedef __attribute__((ext_vector_type(4))) float f32x4;

__device__ __forceinline__ int seqmap(int t) { return 1023 - 32 * (t & 31) - (t >> 5); }

__device__ __forceinline__ ushortT f2bf(float f) {
  union { float f; unsigned u; } v; v.f = f;
  unsigned r = v.u + 0x7FFF + ((v.u >> 16) & 1);
  return (ushortT)(r >> 16);
}

__device__ __forceinline__ void gload_lds16(const void* g, void* l) {
  __builtin_amdgcn_global_load_lds((const __attribute__((address_space(1))) void*)g,
                                   (__attribute__((address_space(3))) void*)l, 16, 0, 0);
}

// ---------------- weight convert (f32 -> bf16, zero-pad tail) ----------------
__global__ __launch_bounds__(256) void cvt_bf16_kernel(const float* __restrict__ src,
                                                       ushortT* __restrict__ dst,
                                                       long nsrc, long ndst) {
  long i = (long)blockIdx.x * 256 + threadIdx.x;
  long stride = (long)gridDim.x * 256;
  for (; i < ndst; i += stride) dst[i] = (i < nsrc) ? f2bf(src[i]) : (ushortT)0;
}

// ---------------- LayerNorm (both dirs; dir1 gathers via SEQ) ----------------
__global__ __launch_bounds__(256) void ln_kernel(const float* __restrict__ x,
    const float* __restrict__ wf, const float* __restrict__ bf_,
    const float* __restrict__ wb, const float* __restrict__ bb,
    ushortT* __restrict__ xln) {
  __shared__ float lds[4];
  int bid = blockIdx.x;
  int dir = bid >> 11, row = bid & 2047;
  int b = row >> 10, t = row & 1023;
  int st = dir ? seqmap(t) : t;
  const float* xr = x + (size_t)(b * 1024 + st) * DM;
  const float* w = dir ? wb : wf;
  const float* bia = dir ? bb : bf_;
  int tid = threadIdx.x;
  float v0 = xr[tid], v1 = xr[tid + 256], v2 = xr[tid + 512];
  float s = v0 + v1 + v2;
  #pragma unroll
  for (int o = 32; o; o >>= 1) s += __shfl_xor(s, o, 64);
  if ((tid & 63) == 0) lds[tid >> 6] = s;
  __syncthreads();
  float mean = (lds[0] + lds[1] + lds[2] + lds[3]) * (1.f / 768.f);
  __syncthreads();
  float d0 = v0 - mean, d1 = v1 - mean, d2 = v2 - mean;
  float q = d0 * d0 + d1 * d1 + d2 * d2;
  #pragma unroll
  for (int o = 32; o; o >>= 1) q += __shfl_xor(q, o, 64);
  if ((tid & 63) == 0) lds[tid >> 6] = q;
  __syncthreads();
  float var = (lds[0] + lds[1] + lds[2] + lds[3]) * (1.f / 768.f);
  float rs = rsqrtf(var + EPSF);
  ushortT* orow = xln + (size_t)bid * DM;
  orow[tid]       = f2bf(d0 * rs * w[tid]       + bia[tid]);
  orow[tid + 256] = f2bf(d1 * rs * w[tid + 256] + bia[tid + 256]);
  orow[tid + 512] = f2bf(d2 * rs * w[tid + 512] + bia[tid + 512]);
}

// ---------------- bf16 MFMA GEMM: C[M,N] = A[M,K] * B[N,K]^T ----------------
// 128x128 tile, 4 waves (2x2), 16x16x32 MFMA, global_load_lds staging.
__global__ __launch_bounds__(256) void gemm_bf16(
    const ushortT* __restrict__ Aall, const ushortT* __restrict__ Ball,
    float* __restrict__ Call,
    int K, int lda, int ldb, int ldc, long sA, long sB, long sC) {
  __shared__ ushortT sAt[128 * 32];
  __shared__ ushortT sBt[128 * 32];
  const ushortT* A = Aall + (size_t)blockIdx.z * sA;
  const ushortT* B = Ball + (size_t)blockIdx.z * sB;
  float* C = Call + (size_t)blockIdx.z * sC;
  int tid = threadIdx.x, lane = tid & 63, w = tid >> 6;
  int wm = w >> 1, wn = w & 1;
  int m0 = blockIdx.y * 128, n0 = blockIdx.x * 128;
  int rA = lane >> 2, cA = (lane & 3) * 8;
  f32x4 acc[4][4] = {};
  for (int kt = 0; kt < K; kt += 32) {
    __syncthreads();
    #pragma unroll
    for (int c = 0; c < 2; ++c) {
      int q = w * 2 + c;
      const ushortT* ga = A + (size_t)(m0 + q * 16 + rA) * lda + kt + cA;
      const ushortT* gb = B + (size_t)(n0 + q * 16 + rA) * ldb + kt + cA;
      gload_lds16(ga, &sAt[q * 512]);
      gload_lds16(gb, &sBt[q * 512]);
    }
    __syncthreads();
    int fr = lane & 15, kk = (lane >> 4) * 8;
    bf16x8 af[4], bfr[4];
    #pragma unroll
    for (int i = 0; i < 4; ++i)
      af[i] = *(const bf16x8*)&sAt[(wm * 64 + i * 16 + fr) * 32 + kk];
    #pragma unroll
    for (int j = 0; j < 4; ++j)
      bfr[j] = *(const bf16x8*)&sBt[(wn * 64 + j * 16 + fr) * 32 + kk];
    #pragma unroll
    for (int i = 0; i < 4; ++i)
      #pragma unroll
      for (int j = 0; j < 4; ++j)
        acc[i][j] = __builtin_amdgcn_mfma_f32_16x16x32_bf16(af[i], bfr[j], acc[i][j], 0, 0, 0);
  }
  int cr = (lane >> 4) * 4, cc = lane & 15;
  #pragma unroll
  for (int i = 0; i < 4; ++i)
    #pragma unroll
    for (int j = 0; j < 4; ++j) {
      float* Cp = C + (size_t)(m0 + wm * 64 + i * 16 + cr) * ldc + (n0 + wn * 64 + j * 16 + cc);
      #pragma unroll
      for (int r = 0; r < 4; ++r) Cp[(size_t)r * ldc] = acc[i][j][r];
    }
}

// ---------------- conv(K=4 causal, depthwise) + silu + dt/dA precompute ----------------
__global__ __launch_bounds__(256) void conv_dt_kernel(const float* __restrict__ zx,
    const float* __restrict__ cwf, const float* __restrict__ cbf,
    const float* __restrict__ cwb, const float* __restrict__ cbb,
    const float* __restrict__ dtbf, const float* __restrict__ alogf,
    const float* __restrict__ dtbb, const float* __restrict__ alogb,
    float* __restrict__ xconv, float* __restrict__ dts, float* __restrict__ dAs) {
  int bid = blockIdx.x;
  int dir = bid >> 11, row = bid & 2047;
  int t = row & 1023;
  const float* cw   = dir ? cwb : cwf;
  const float* cb   = dir ? cbb : cbf;
  const float* dtb  = dir ? dtbb : dtbf;
  const float* alog = dir ? alogb : alogf;
  const float* zrow = zx + (size_t)bid * NP1;
  int tid = threadIdx.x;
  if (tid < HH) {
    float raw = zrow[3200 + tid] + dtb[tid];
    float dtv = raw > 20.f ? raw : log1pf(expf(raw));
    dts[(size_t)bid * HH + tid] = dtv;
    dAs[(size_t)bid * HH + tid] = expf(-expf(alog[tid]) * dtv);
  }
  float* xrow = xconv + (size_t)bid * CONVD;
  for (int c = tid; c < CONVD; c += 256) {
    float acc = cb[c];
    #pragma unroll
    for (int k = 0; k < 4; ++k) {
      int tt = t - 3 + k;
      if (tt >= 0) acc += zrow[(long)(k - 3) * NP1 + 1536 + c] * cw[c * 4 + k];
    }
    xrow[c] = acc / (1.f + expf(-acc));
  }
}

// ---------------- sequential SSM scan: block per (dir,b,h) ----------------
// wave w owns n in [16w,16w+16), lane = p. LDS y-flush every 16 steps.
__global__ __launch_bounds__(256) void scan_kernel(const float* __restrict__ xconv,
    const float* __restrict__ dts, const float* __restrict__ dAs,
    float* __restrict__ y) {
  __shared__ float ypart[16][4][64];
  int bid = blockIdx.x;                 // dir*48 + b*24 + h
  int dir = bid / 48;
  int rem = bid % 48;
  int b = rem / 24, h = rem % 24;
  int tid = threadIdx.x, lane = tid & 63;
  int w = __builtin_amdgcn_readfirstlane(tid >> 6);
  size_t rowbase = ((size_t)dir * 2 + b) * 1024;
  const float* xc = xconv + rowbase * CONVD;
  float S[16];
  #pragma unroll
  for (int i = 0; i < 16; ++i) S[i] = 0.f;
  for (int t0 = 0; t0 < 1024; t0 += 16) {
    #pragma unroll
    for (int ti = 0; ti < 16; ++ti) {
      int t = t0 + ti;
      const float* xrow = xc + (size_t)t * CONVD;
      float dtv = dts[(rowbase + t) * HH + h];
      float dAv = dAs[(rowbase + t) * HH + h];
      float xv = xrow[h * 64 + lane];
      const float* Bt = xrow + 1536 + w * 16;
      const float* Ct = xrow + 1600 + w * 16;
      float dtx = dtv * xv;
      float yp = 0.f;
      #pragma unroll
      for (int i = 0; i < 16; ++i) {
        float bv = Bt[i], cv = Ct[i];
        S[i] = __builtin_fmaf(S[i], dAv, bv * dtx);
        yp = __builtin_fmaf(cv, S[i], yp);
      }
      ypart[ti][w][lane] = yp;
    }
    __syncthreads();
    for (int idx = tid; idx < 1024; idx += 256) {
      int ti = idx >> 6, p = idx & 63;
      float ysum = ypart[ti][0][p] + ypart[ti][1][p] + ypart[ti][2][p] + ypart[ti][3][p];
      y[(rowbase + t0 + ti) * DI + h * 64 + p] = ysum;
    }
    __syncthreads();
  }
}

// ---------------- +D*xs, gate silu(z), RMSNorm, -> bf16 ----------------
__global__ __launch_bounds__(256) void gate_norm_kernel(const float* __restrict__ y,
    const float* __restrict__ zx, const float* __restrict__ xconv,
    const float* __restrict__ Df, const float* __restrict__ Db,
    const float* __restrict__ nwf, const float* __restrict__ nwb,
    ushortT* __restrict__ yn) {
  __shared__ float lds[4];
  int bid = blockIdx.x;
  int dir = bid >> 11;
  const float* Dp = dir ? Db : Df;
  const float* nw = dir ? nwb : nwf;
  const float* yr = y + (size_t)bid * DI;
  const float* zr = zx + (size_t)bid * NP1;
  const float* xcr = xconv + (size_t)bid * CONVD;
  int tid = threadIdx.x;
  float vals[6];
  float ss = 0.f;
  #pragma unroll
  for (int i = 0; i < 6; ++i) {
    int c = i * 256 + tid;
    float yv = yr[c] + Dp[c >> 6] * xcr[c];
    float zv = zr[c];
    yv *= zv / (1.f + expf(-zv));
    vals[i] = yv;
    ss += yv * yv;
  }
  #pragma unroll
  for (int o = 32; o; o >>= 1) ss += __shfl_xor(ss, o, 64);
  if ((tid & 63) == 0) lds[tid >> 6] = ss;
  __syncthreads();
  float ms = (lds[0] + lds[1] + lds[2] + lds[3]) * (1.f / 1536.f);
  float sc = rsqrtf(ms + EPSF);
  ushortT* orow = yn + (size_t)bid * DI;
  #pragma unroll
  for (int i = 0; i < 6; ++i) {
    int c = i * 256 + tid;
    orow[c] = f2bf(vals[i] * sc * nw[c]);
  }
}

// ---------------- out[t] = 2x[t] + mf[t] + mb[SEQ[t]] ----------------
__global__ __launch_bounds__(256) void combine_kernel(const float* __restrict__ x,
    const float* __restrict__ mf, const float* __restrict__ mb,
    float* __restrict__ out) {
  int bid = blockIdx.x;   // b*1024 + t
  int b = bid >> 10, t = bid & 1023;
  int st = seqmap(t);
  const float* xr = x + (size_t)bid * DM;
  const float* fr = mf + (size_t)bid * DM;
  const float* br = mb + (size_t)(b * 1024 + st) * DM;
  float* orow = out + (size_t)bid * DM;
  for (int c = threadIdx.x; c < DM; c += 256)
    orow[c] = 2.f * xr[c] + fr[c] + br[c];
}

extern "C" void kernel_launch(void* const* d_in, const int* in_sizes, int n_in,
                              void* d_out, int out_size, void* d_ws, size_t ws_size,
                              hipStream_t stream) {
  const float* x       = (const float*)d_in[0];
  const float* f_ln_w  = (const float*)d_in[1];
  const float* f_ln_b  = (const float*)d_in[2];
  const float* f_in_w  = (const float*)d_in[3];
  const float* f_cw    = (const float*)d_in[4];
  const float* f_cb    = (const float*)d_in[5];
  const float* f_dtb   = (const float*)d_in[6];
  const float* f_alog  = (const float*)d_in[7];
  const float* f_D     = (const float*)d_in[8];
  const float* f_nw    = (const float*)d_in[9];
  const float* f_ow    = (const float*)d_in[10];
  const float* b_ln_w  = (const float*)d_in[11];
  const float* b_ln_b  = (const float*)d_in[12];
  const float* b_in_w  = (const float*)d_in[13];
  const float* b_cw    = (const float*)d_in[14];
  const float* b_cb    = (const float*)d_in[15];
  const float* b_dtb   = (const float*)d_in[16];
  const float* b_alog  = (const float*)d_in[17];
  const float* b_D     = (const float*)d_in[18];
  const float* b_nw    = (const float*)d_in[19];
  const float* b_ow    = (const float*)d_in[20];

  char* ws = (char*)d_ws;
  size_t off = 0;
  auto carve = [&](size_t bytes) -> char* {
    off = (off + 255) & ~(size_t)255;
    char* p = ws + off;
    off += bytes;
    return p;
  };
  ushortT* XLN  = (ushortT*)carve((size_t)2 * ROWS * DM * 2);
  ushortT* WP1  = (ushortT*)carve((size_t)2 * NP1 * DM * 2);
  ushortT* W2   = (ushortT*)carve((size_t)2 * DM * DI * 2);
  float*   ZX   = (float*)carve((size_t)2 * ROWS * NP1 * 4);
  float*   XC   = (float*)carve((size_t)2 * ROWS * CONVD * 4);
  float*   DTS  = (float*)carve((size_t)2 * ROWS * HH * 4);
  float*   DAS  = (float*)carve((size_t)2 * ROWS * HH * 4);
  float*   Y    = (float*)carve((size_t)2 * ROWS * DI * 4);
  ushortT* YN   = (ushortT*)carve((size_t)2 * ROWS * DI * 2);
  float*   MOUT = (float*)carve((size_t)2 * ROWS * DM * 4);

  // weight conversion
  cvt_bf16_kernel<<<1024, 256, 0, stream>>>(f_in_w, WP1, (long)DINP * DM, (long)NP1 * DM);
  cvt_bf16_kernel<<<1024, 256, 0, stream>>>(b_in_w, WP1 + (size_t)NP1 * DM, (long)DINP * DM, (long)NP1 * DM);
  cvt_bf16_kernel<<<1024, 256, 0, stream>>>(f_ow, W2, (long)DM * DI, (long)DM * DI);
  cvt_bf16_kernel<<<1024, 256, 0, stream>>>(b_ow, W2 + (size_t)DM * DI, (long)DM * DI, (long)DM * DI);

  // layernorm (both dirs)
  ln_kernel<<<4096, 256, 0, stream>>>(x, f_ln_w, f_ln_b, b_ln_w, b_ln_b, XLN);

  // in_proj: [2048,768] x [3328,768]^T -> [2048,3328]
  gemm_bf16<<<dim3(NP1 / 128, ROWS / 128, 2), 256, 0, stream>>>(
      XLN, WP1, ZX, DM, DM, DM, NP1,
      (long)ROWS * DM, (long)NP1 * DM, (long)ROWS * NP1);

  // conv + dt
  conv_dt_kernel<<<4096, 256, 0, stream>>>(ZX, f_cw, f_cb, b_cw, b_cb,
                                           f_dtb, f_alog, b_dtb, b_alog,
                                           XC, DTS, DAS);

  // scan
  scan_kernel<<<96, 256, 0, stream>>>(XC, DTS, DAS, Y);

  // gate + rmsnorm
  gate_norm_kernel<<<4096, 256, 0, stream>>>(Y, ZX, XC, f_D, b_D, f_nw, b_nw, YN);

  // out_proj: [2048,1536] x [768,1536]^T -> [2048,768]
  gemm_bf16<<<dim3(DM / 128, ROWS / 128, 2), 256, 0, stream>>>(
      YN, W2, MOUT, DI, DI, DI, DM,
      (long)ROWS * DI, (long)DM * DI, (long)ROWS * DM);

  // combine
  combine_kernel<<<2048, 256, 0, stream>>>(x, MOUT, MOUT + (size_t)ROWS * DM, (float*)d_out);
}

// Round 2
// 264.103 us; speedup vs baseline: 2.3149x; 2.3149x over previous
//
#include <hip/hip_runtime.h>
#include <cstdint>

#define DM    768
#define DI    1536
#define PP    64
#define HH    24
#define NN    64
#define CONVD 1664
#define DINP  3224
#define NP1   3328   // 3224 padded to 26*128
#define LL    1024
#define ROWS  2048   // BATCH*LL
#define EPSF  1e-5f
#define NCHUNK 16
#define CLEN   64

typedef unsigned short ushortT;
typedef __attribute__((ext_vector_type(8))) __bf16 bf16x8;
typedef __attribute__((ext_vector_type(4))) float f32x4;

__device__ __forceinline__ int seqmap(int t) { return 1023 - 32 * (t & 31) - (t >> 5); }

__device__ __forceinline__ ushortT f2bf(float f) {
  union { float f; unsigned u; } v; v.f = f;
  unsigned r = v.u + 0x7FFF + ((v.u >> 16) & 1);
  return (ushortT)(r >> 16);
}

__device__ __forceinline__ void gload_lds16(const void* g, void* l) {
  __builtin_amdgcn_global_load_lds((const __attribute__((address_space(1))) void*)g,
                                   (__attribute__((address_space(3))) void*)l, 16, 0, 0);
}

// ---------------- weight convert (f32 -> bf16, zero-pad tail) ----------------
__global__ __launch_bounds__(256) void cvt_bf16_kernel(const float* __restrict__ src,
                                                       ushortT* __restrict__ dst,
                                                       long nsrc, long ndst) {
  long i = (long)blockIdx.x * 256 + threadIdx.x;
  long stride = (long)gridDim.x * 256;
  for (; i < ndst; i += stride) dst[i] = (i < nsrc) ? f2bf(src[i]) : (ushortT)0;
}

// ---------------- LayerNorm (both dirs; dir1 gathers via SEQ) ----------------
__global__ __launch_bounds__(256) void ln_kernel(const float* __restrict__ x,
    const float* __restrict__ wf, const float* __restrict__ bf_,
    const float* __restrict__ wb, const float* __restrict__ bb,
    ushortT* __restrict__ xln) {
  __shared__ float lds[4];
  int bid = blockIdx.x;
  int dir = bid >> 11, row = bid & 2047;
  int b = row >> 10, t = row & 1023;
  int st = dir ? seqmap(t) : t;
  const float* xr = x + (size_t)(b * 1024 + st) * DM;
  const float* w = dir ? wb : wf;
  const float* bia = dir ? bb : bf_;
  int tid = threadIdx.x;
  float v0 = xr[tid], v1 = xr[tid + 256], v2 = xr[tid + 512];
  float s = v0 + v1 + v2;
  #pragma unroll
  for (int o = 32; o; o >>= 1) s += __shfl_xor(s, o, 64);
  if ((tid & 63) == 0) lds[tid >> 6] = s;
  __syncthreads();
  float mean = (lds[0] + lds[1] + lds[2] + lds[3]) * (1.f / 768.f);
  __syncthreads();
  float d0 = v0 - mean, d1 = v1 - mean, d2 = v2 - mean;
  float q = d0 * d0 + d1 * d1 + d2 * d2;
  #pragma unroll
  for (int o = 32; o; o >>= 1) q += __shfl_xor(q, o, 64);
  if ((tid & 63) == 0) lds[tid >> 6] = q;
  __syncthreads();
  float var = (lds[0] + lds[1] + lds[2] + lds[3]) * (1.f / 768.f);
  float rs = rsqrtf(var + EPSF);
  ushortT* orow = xln + (size_t)bid * DM;
  orow[tid]       = f2bf(d0 * rs * w[tid]       + bia[tid]);
  orow[tid + 256] = f2bf(d1 * rs * w[tid + 256] + bia[tid + 256]);
  orow[tid + 512] = f2bf(d2 * rs * w[tid + 512] + bia[tid + 512]);
}

// ---------------- bf16 MFMA GEMM: C[M,N] = A[M,K] * B[N,K]^T ----------------
__global__ __launch_bounds__(256) void gemm_bf16(
    const ushortT* __restrict__ Aall, const ushortT* __restrict__ Ball,
    float* __restrict__ Call,
    int K, int lda, int ldb, int ldc, long sA, long sB, long sC) {
  __shared__ ushortT sAt[128 * 32];
  __shared__ ushortT sBt[128 * 32];
  const ushortT* A = Aall + (size_t)blockIdx.z * sA;
  const ushortT* B = Ball + (size_t)blockIdx.z * sB;
  float* C = Call + (size_t)blockIdx.z * sC;
  int tid = threadIdx.x, lane = tid & 63, w = tid >> 6;
  int wm = w >> 1, wn = w & 1;
  int m0 = blockIdx.y * 128, n0 = blockIdx.x * 128;
  int rA = lane >> 2, cA = (lane & 3) * 8;
  f32x4 acc[4][4] = {};
  for (int kt = 0; kt < K; kt += 32) {
    __syncthreads();
    #pragma unroll
    for (int c = 0; c < 2; ++c) {
      int q = w * 2 + c;
      const ushortT* ga = A + (size_t)(m0 + q * 16 + rA) * lda + kt + cA;
      const ushortT* gb = B + (size_t)(n0 + q * 16 + rA) * ldb + kt + cA;
      gload_lds16(ga, &sAt[q * 512]);
      gload_lds16(gb, &sBt[q * 512]);
    }
    __syncthreads();
    int fr = lane & 15, kk = (lane >> 4) * 8;
    bf16x8 af[4], bfr[4];
    #pragma unroll
    for (int i = 0; i < 4; ++i)
      af[i] = *(const bf16x8*)&sAt[(wm * 64 + i * 16 + fr) * 32 + kk];
    #pragma unroll
    for (int j = 0; j < 4; ++j)
      bfr[j] = *(const bf16x8*)&sBt[(wn * 64 + j * 16 + fr) * 32 + kk];
    #pragma unroll
    for (int i = 0; i < 4; ++i)
      #pragma unroll
      for (int j = 0; j < 4; ++j)
        acc[i][j] = __builtin_amdgcn_mfma_f32_16x16x32_bf16(af[i], bfr[j], acc[i][j], 0, 0, 0);
  }
  int cr = (lane >> 4) * 4, cc = lane & 15;
  #pragma unroll
  for (int i = 0; i < 4; ++i)
    #pragma unroll
    for (int j = 0; j < 4; ++j) {
      float* Cp = C + (size_t)(m0 + wm * 64 + i * 16 + cr) * ldc + (n0 + wn * 64 + j * 16 + cc);
      #pragma unroll
      for (int r = 0; r < 4; ++r) Cp[(size_t)r * ldc] = acc[i][j][r];
    }
}

// ---------------- conv(K=4 causal, depthwise) + silu + dt/dA precompute ----------------
__global__ __launch_bounds__(256) void conv_dt_kernel(const float* __restrict__ zx,
    const float* __restrict__ cwf, const float* __restrict__ cbf,
    const float* __restrict__ cwb, const float* __restrict__ cbb,
    const float* __restrict__ dtbf, const float* __restrict__ alogf,
    const float* __restrict__ dtbb, const float* __restrict__ alogb,
    float* __restrict__ xconv, float* __restrict__ dts, float* __restrict__ dAs) {
  int bid = blockIdx.x;
  int dir = bid >> 11, row = bid & 2047;
  int t = row & 1023;
  const float* cw   = dir ? cwb : cwf;
  const float* cb   = dir ? cbb : cbf;
  const float* dtb  = dir ? dtbb : dtbf;
  const float* alog = dir ? alogb : alogf;
  const float* zrow = zx + (size_t)bid * NP1;
  int tid = threadIdx.x;
  if (tid < HH) {
    float raw = zrow[3200 + tid] + dtb[tid];
    float dtv = raw > 20.f ? raw : log1pf(expf(raw));
    dts[(size_t)bid * HH + tid] = dtv;
    dAs[(size_t)bid * HH + tid] = expf(-expf(alog[tid]) * dtv);
  }
  float* xrow = xconv + (size_t)bid * CONVD;
  for (int c = tid; c < CONVD; c += 256) {
    float acc = cb[c];
    #pragma unroll
    for (int k = 0; k < 4; ++k) {
      int tt = t - 3 + k;
      if (tt >= 0) acc += zrow[(long)(k - 3) * NP1 + 1536 + c] * cw[c * 4 + k];
    }
    xrow[c] = acc / (1.f + expf(-acc));
  }
}

// ---------------- pass 1: chunked SSM scan, block per (dir,b,h,chunk) ----------------
// wave w owns n in [16w,16w+16), lane = p. Local scan from zero init over 64 steps.
// Writes: local y, chunk-final local state S_loc, within-chunk decay cumprod cw[t].
__global__ __launch_bounds__(256) void scan_chunk_kernel(const float* __restrict__ xconv,
    const float* __restrict__ dts, const float* __restrict__ dAs,
    float* __restrict__ y, float* __restrict__ sloc, float* __restrict__ cwb_) {
  __shared__ float ypart[16][4][64];
  int gh = blockIdx.x;                 // dir*48 + b*24 + h
  int c  = blockIdx.y;                 // chunk 0..15
  int dir = gh / 48;
  int rem = gh % 48;
  int b = rem / 24, h = rem % 24;
  int tid = threadIdx.x, lane = tid & 63;
  int w = __builtin_amdgcn_readfirstlane(tid >> 6);
  size_t rowbase = ((size_t)dir * 2 + b) * 1024;
  const float* xc = xconv + rowbase * CONVD;
  float S[16];
  #pragma unroll
  for (int i = 0; i < 16; ++i) S[i] = 0.f;
  float cwr = 1.f;
  for (int t0 = c * CLEN; t0 < c * CLEN + CLEN; t0 += 16) {
    #pragma unroll
    for (int ti = 0; ti < 16; ++ti) {
      int t = t0 + ti;
      const float* xrow = xc + (size_t)t * CONVD;
      float dtv = dts[(rowbase + t) * HH + h];
      float dAv = dAs[(rowbase + t) * HH + h];
      float xv = xrow[h * 64 + lane];
      const float* Bt = xrow + 1536 + w * 16;
      const float* Ct = xrow + 1600 + w * 16;
      float dtx = dtv * xv;
      cwr *= dAv;
      if (tid == 0) cwb_[(rowbase + t) * HH + h] = cwr;
      float yp = 0.f;
      #pragma unroll
      for (int i = 0; i < 16; ++i) {
        float bv = Bt[i], cv = Ct[i];
        S[i] = __builtin_fmaf(S[i], dAv, bv * dtx);
        yp = __builtin_fmaf(cv, S[i], yp);
      }
      ypart[ti][w][lane] = yp;
    }
    __syncthreads();
    for (int idx = tid; idx < 1024; idx += 256) {
      int ti = idx >> 6, p = idx & 63;
      float ysum = ypart[ti][0][p] + ypart[ti][1][p] + ypart[ti][2][p] + ypart[ti][3][p];
      y[(rowbase + t0 + ti) * DI + h * 64 + p] = ysum;
    }
    __syncthreads();
  }
  // store local chunk-final state: S[i] is n = w*16+i, p = lane
  float* sp = sloc + ((size_t)gh * NCHUNK + c) * 4096;
  #pragma unroll
  for (int i = 0; i < 16; ++i) sp[(w * 16 + i) * 64 + lane] = S[i];
}

// ---------------- pass 2: serial prefix over chunk states (96 blocks) ----------------
// In-place: slot c-1 ends holding S_init for chunk c.
__global__ __launch_bounds__(256) void chunk_prefix_kernel(float* __restrict__ sloc,
    const float* __restrict__ cwb_) {
  int gh = blockIdx.x;
  int dir = gh / 48;
  int rem = gh % 48;
  int b = rem / 24, h = rem % 24;
  int tid = threadIdx.x;
  size_t rowbase = ((size_t)dir * 2 + b) * 1024;
  float R[16];
  #pragma unroll
  for (int j = 0; j < 16; ++j) R[j] = 0.f;
  for (int c = 1; c < NCHUNK; ++c) {
    float W = cwb_[(rowbase + (size_t)c * CLEN - 1) * HH + h];
    float* slot = sloc + ((size_t)gh * NCHUNK + (c - 1)) * 4096;
    #pragma unroll
    for (int j = 0; j < 16; ++j) {
      float Lv = slot[j * 256 + tid];
      R[j] = __builtin_fmaf(R[j], W, Lv);
      slot[j * 256 + tid] = R[j];
    }
  }
}

// ---------------- pass 3: y[t] += cw[t] * C_t . S_init  (chunks 1..15) ----------------
__global__ __launch_bounds__(256) void fixup_kernel(const float* __restrict__ xconv,
    const float* __restrict__ cwb_, const float* __restrict__ sloc,
    float* __restrict__ y) {
  __shared__ float sS[4096];   // [n][p]
  __shared__ float sC[4096];   // [t][n]
  int gh = blockIdx.x;
  int c = blockIdx.y + 1;      // 1..15
  int dir = gh / 48;
  int rem = gh % 48;
  int b = rem / 24, h = rem % 24;
  int tid = threadIdx.x, lane = tid & 63;
  int w = tid >> 6;
  size_t rowbase = ((size_t)dir * 2 + b) * 1024;
  const float* slot = sloc + ((size_t)gh * NCHUNK + (c - 1)) * 4096;
  #pragma unroll
  for (int j = 0; j < 16; ++j) sS[j * 256 + tid] = slot[j * 256 + tid];
  for (int idx = tid; idx < 4096; idx += 256) {
    int tl = idx >> 6, n = idx & 63;
    sC[idx] = xconv[(rowbase + c * CLEN + tl) * CONVD + 1600 + n];
  }
  __syncthreads();
  #pragma unroll
  for (int k = 0; k < 16; ++k) {
    int tl = w * 16 + k;
    int t = c * CLEN + tl;
    float acc = 0.f;
    #pragma unroll 8
    for (int n = 0; n < 64; ++n)
      acc = __builtin_fmaf(sC[tl * 64 + n], sS[n * 64 + lane], acc);
    size_t yi = (rowbase + t) * DI + h * 64 + lane;
    float cwv = cwb_[(rowbase + t) * HH + h];
    y[yi] = __builtin_fmaf(cwv, acc, y[yi]);
  }
}

// ---------------- +D*xs, gate silu(z), RMSNorm, -> bf16 ----------------
__global__ __launch_bounds__(256) void gate_norm_kernel(const float* __restrict__ y,
    const float* __restrict__ zx, const float* __restrict__ xconv,
    const float* __restrict__ Df, const float* __restrict__ Db,
    const float* __restrict__ nwf, const float* __restrict__ nwb,
    ushortT* __restrict__ yn) {
  __shared__ float lds[4];
  int bid = blockIdx.x;
  int dir = bid >> 11;
  const float* Dp = dir ? Db : Df;
  const float* nw = dir ? nwb : nwf;
  const float* yr = y + (size_t)bid * DI;
  const float* zr = zx + (size_t)bid * NP1;
  const float* xcr = xconv + (size_t)bid * CONVD;
  int tid = threadIdx.x;
  float vals[6];
  float ss = 0.f;
  #pragma unroll
  for (int i = 0; i < 6; ++i) {
    int c = i * 256 + tid;
    float yv = yr[c] + Dp[c >> 6] * xcr[c];
    float zv = zr[c];
    yv *= zv / (1.f + expf(-zv));
    vals[i] = yv;
    ss += yv * yv;
  }
  #pragma unroll
  for (int o = 32; o; o >>= 1) ss += __shfl_xor(ss, o, 64);
  if ((tid & 63) == 0) lds[tid >> 6] = ss;
  __syncthreads();
  float ms = (lds[0] + lds[1] + lds[2] + lds[3]) * (1.f / 1536.f);
  float sc = rsqrtf(ms + EPSF);
  ushortT* orow = yn + (size_t)bid * DI;
  #pragma unroll
  for (int i = 0; i < 6; ++i) {
    int c = i * 256 + tid;
    orow[c] = f2bf(vals[i] * sc * nw[c]);
  }
}

// ---------------- out[t] = 2x[t] + mf[t] + mb[SEQ[t]] ----------------
__global__ __launch_bounds__(256) void combine_kernel(const float* __restrict__ x,
    const float* __restrict__ mf, const float* __restrict__ mb,
    float* __restrict__ out) {
  int bid = blockIdx.x;   // b*1024 + t
  int b = bid >> 10, t = bid & 1023;
  int st = seqmap(t);
  const float* xr = x + (size_t)bid * DM;
  const float* fr = mf + (size_t)bid * DM;
  const float* br = mb + (size_t)(b * 1024 + st) * DM;
  float* orow = out + (size_t)bid * DM;
  for (int c = threadIdx.x; c < DM; c += 256)
    orow[c] = 2.f * xr[c] + fr[c] + br[c];
}

extern "C" void kernel_launch(void* const* d_in, const int* in_sizes, int n_in,
                              void* d_out, int out_size, void* d_ws, size_t ws_size,
                              hipStream_t stream) {
  const float* x       = (const float*)d_in[0];
  const float* f_ln_w  = (const float*)d_in[1];
  const float* f_ln_b  = (const float*)d_in[2];
  const float* f_in_w  = (const float*)d_in[3];
  const float* f_cw    = (const float*)d_in[4];
  const float* f_cb    = (const float*)d_in[5];
  const float* f_dtb   = (const float*)d_in[6];
  const float* f_alog  = (const float*)d_in[7];
  const float* f_D     = (const float*)d_in[8];
  const float* f_nw    = (const float*)d_in[9];
  const float* f_ow    = (const float*)d_in[10];
  const float* b_ln_w  = (const float*)d_in[11];
  const float* b_ln_b  = (const float*)d_in[12];
  const float* b_in_w  = (const float*)d_in[13];
  const float* b_cw    = (const float*)d_in[14];
  const float* b_cb    = (const float*)d_in[15];
  const float* b_dtb   = (const float*)d_in[16];
  const float* b_alog  = (const float*)d_in[17];
  const float* b_D     = (const float*)d_in[18];
  const float* b_nw    = (const float*)d_in[19];
  const float* b_ow    = (const float*)d_in[20];

  char* ws = (char*)d_ws;
  size_t off = 0;
  auto carve = [&](size_t bytes) -> char* {
    off = (off + 255) & ~(size_t)255;
    char* p = ws + off;
    off += bytes;
    return p;
  };
  ushortT* XLN  = (ushortT*)carve((size_t)2 * ROWS * DM * 2);
  ushortT* WP1  = (ushortT*)carve((size_t)2 * NP1 * DM * 2);
  ushortT* W2   = (ushortT*)carve((size_t)2 * DM * DI * 2);
  float*   ZX   = (float*)carve((size_t)2 * ROWS * NP1 * 4);
  float*   XC   = (float*)carve((size_t)2 * ROWS * CONVD * 4);
  float*   DTS  = (float*)carve((size_t)2 * ROWS * HH * 4);
  float*   DAS  = (float*)carve((size_t)2 * ROWS * HH * 4);
  float*   Y    = (float*)carve((size_t)2 * ROWS * DI * 4);
  ushortT* YN   = (ushortT*)carve((size_t)2 * ROWS * DI * 2);
  float*   MOUT = (float*)carve((size_t)2 * ROWS * DM * 4);
  float*   SLOC = (float*)carve((size_t)96 * NCHUNK * 4096 * 4);
  float*   CW   = (float*)carve((size_t)2 * ROWS * HH * 4);

  // weight conversion
  cvt_bf16_kernel<<<1024, 256, 0, stream>>>(f_in_w, WP1, (long)DINP * DM, (long)NP1 * DM);
  cvt_bf16_kernel<<<1024, 256, 0, stream>>>(b_in_w, WP1 + (size_t)NP1 * DM, (long)DINP * DM, (long)NP1 * DM);
  cvt_bf16_kernel<<<1024, 256, 0, stream>>>(f_ow, W2, (long)DM * DI, (long)DM * DI);
  cvt_bf16_kernel<<<1024, 256, 0, stream>>>(b_ow, W2 + (size_t)DM * DI, (long)DM * DI, (long)DM * DI);

  // layernorm (both dirs)
  ln_kernel<<<4096, 256, 0, stream>>>(x, f_ln_w, f_ln_b, b_ln_w, b_ln_b, XLN);

  // in_proj: [2048,768] x [3328,768]^T -> [2048,3328]
  gemm_bf16<<<dim3(NP1 / 128, ROWS / 128, 2), 256, 0, stream>>>(
      XLN, WP1, ZX, DM, DM, DM, NP1,
      (long)ROWS * DM, (long)NP1 * DM, (long)ROWS * NP1);

  // conv + dt
  conv_dt_kernel<<<4096, 256, 0, stream>>>(ZX, f_cw, f_cb, b_cw, b_cb,
                                           f_dtb, f_alog, b_dtb, b_alog,
                                           XC, DTS, DAS);

  // chunked scan: pass 1 (local scans), pass 2 (chunk-state prefix), pass 3 (fixup)
  scan_chunk_kernel<<<dim3(96, NCHUNK), 256, 0, stream>>>(XC, DTS, DAS, Y, SLOC, CW);
  chunk_prefix_kernel<<<96, 256, 0, stream>>>(SLOC, CW);
  fixup_kernel<<<dim3(96, NCHUNK - 1), 256, 0, stream>>>(XC, CW, SLOC, Y);

  // gate + rmsnorm
  gate_norm_kernel<<<4096, 256, 0, stream>>>(Y, ZX, XC, f_D, b_D, f_nw, b_nw, YN);

  // out_proj: [2048,1536] x [768,1536]^T -> [2048,768]
  gemm_bf16<<<dim3(DM / 128, ROWS / 128, 2), 256, 0, stream>>>(
      YN, W2, MOUT, DI, DI, DI, DM,
      (long)ROWS * DI, (long)DM * DI, (long)ROWS * DM);

  // combine
  combine_kernel<<<2048, 256, 0, stream>>>(x, MOUT, MOUT + (size_t)ROWS * DM, (float*)d_out);
}

// Round 3
// 226.000 us; speedup vs baseline: 2.7052x; 1.1686x over previous
//
#include <hip/hip_runtime.h>
#include <cstdint>

#define DM    768
#define DI    1536
#define PP    64
#define HH    24
#define NN    64
#define CONVD 1664
#define DINP  3224
#define NP1   3328   // 3224 padded to 26*128
#define LL    1024
#define ROWS  2048   // BATCH*LL
#define EPSF  1e-5f
#define NCHUNK 16
#define CLEN   64

typedef unsigned short ushortT;
typedef __attribute__((ext_vector_type(8))) __bf16 bf16x8;
typedef __attribute__((ext_vector_type(4))) float f32x4;

__device__ __forceinline__ int seqmap(int t) { return 1023 - 32 * (t & 31) - (t >> 5); }

__device__ __forceinline__ ushortT f2bf(float f) {
  union { float f; unsigned u; } v; v.f = f;
  unsigned r = v.u + 0x7FFF + ((v.u >> 16) & 1);
  return (ushortT)(r >> 16);
}
__device__ __forceinline__ float bf2f(ushortT b) {
  union { unsigned u; float f; } v; v.u = ((unsigned)b) << 16;
  return v.f;
}

__device__ __forceinline__ void gload_lds16(const void* g, void* l) {
  __builtin_amdgcn_global_load_lds((const __attribute__((address_space(1))) void*)g,
                                   (__attribute__((address_space(3))) void*)l, 16, 0, 0);
}

// swizzled ushort index into a 64x64 bf16 tile (row stride 64): T2 XOR swizzle
#define SWZ(r, c) ((r) * 64 + ((c) ^ (((r) & 7) << 3)))

// ---------------- merged weight convert (f32 -> bf16, zero-pad tail) ----------------
__global__ __launch_bounds__(256) void cvt_all_kernel(
    const float* __restrict__ fw1, const float* __restrict__ bw1,
    const float* __restrict__ fw2, const float* __restrict__ bw2,
    ushortT* __restrict__ WP1, ushortT* __restrict__ W2) {
  const long NW1 = (long)NP1 * DM, SW1 = (long)DINP * DM, NW2 = (long)DM * DI;
  const long total = 2 * NW1 + 2 * NW2;
  for (long i = (long)blockIdx.x * 256 + threadIdx.x; i < total; i += (long)gridDim.x * 256) {
    if (i < NW1) {
      WP1[i] = (i < SW1) ? f2bf(fw1[i]) : (ushortT)0;
    } else if (i < 2 * NW1) {
      long j = i - NW1;
      WP1[i] = (j < SW1) ? f2bf(bw1[j]) : (ushortT)0;
    } else if (i < 2 * NW1 + NW2) {
      long j = i - 2 * NW1;
      W2[j] = f2bf(fw2[j]);
    } else {
      long j = i - 2 * NW1 - NW2;
      W2[NW2 + j] = f2bf(bw2[j]);
    }
  }
}

// ---------------- LayerNorm (both dirs; dir1 gathers via SEQ) ----------------
__global__ __launch_bounds__(256) void ln_kernel(const float* __restrict__ x,
    const float* __restrict__ wf, const float* __restrict__ bf_,
    const float* __restrict__ wb, const float* __restrict__ bb,
    ushortT* __restrict__ xln) {
  __shared__ float lds[4];
  int bid = blockIdx.x;
  int dir = bid >> 11, row = bid & 2047;
  int b = row >> 10, t = row & 1023;
  int st = dir ? seqmap(t) : t;
  const float* xr = x + (size_t)(b * 1024 + st) * DM;
  const float* w = dir ? wb : wf;
  const float* bia = dir ? bb : bf_;
  int tid = threadIdx.x;
  float v0 = xr[tid], v1 = xr[tid + 256], v2 = xr[tid + 512];
  float s = v0 + v1 + v2;
  #pragma unroll
  for (int o = 32; o; o >>= 1) s += __shfl_xor(s, o, 64);
  if ((tid & 63) == 0) lds[tid >> 6] = s;
  __syncthreads();
  float mean = (lds[0] + lds[1] + lds[2] + lds[3]) * (1.f / 768.f);
  __syncthreads();
  float d0 = v0 - mean, d1 = v1 - mean, d2 = v2 - mean;
  float q = d0 * d0 + d1 * d1 + d2 * d2;
  #pragma unroll
  for (int o = 32; o; o >>= 1) q += __shfl_xor(q, o, 64);
  if ((tid & 63) == 0) lds[tid >> 6] = q;
  __syncthreads();
  float var = (lds[0] + lds[1] + lds[2] + lds[3]) * (1.f / 768.f);
  float rs = rsqrtf(var + EPSF);
  ushortT* orow = xln + (size_t)bid * DM;
  orow[tid]       = f2bf(d0 * rs * w[tid]       + bia[tid]);
  orow[tid + 256] = f2bf(d1 * rs * w[tid + 256] + bia[tid + 256]);
  orow[tid + 512] = f2bf(d2 * rs * w[tid + 512] + bia[tid + 512]);
}

// ---------------- bf16 MFMA GEMM: C[M,N] = A[M,K] * B[N,K]^T ----------------
__global__ __launch_bounds__(256) void gemm_bf16(
    const ushortT* __restrict__ Aall, const ushortT* __restrict__ Ball,
    float* __restrict__ Call,
    int K, int lda, int ldb, int ldc, long sA, long sB, long sC) {
  __shared__ ushortT sAt[128 * 32];
  __shared__ ushortT sBt[128 * 32];
  const ushortT* A = Aall + (size_t)blockIdx.z * sA;
  const ushortT* B = Ball + (size_t)blockIdx.z * sB;
  float* C = Call + (size_t)blockIdx.z * sC;
  int tid = threadIdx.x, lane = tid & 63, w = tid >> 6;
  int wm = w >> 1, wn = w & 1;
  int m0 = blockIdx.y * 128, n0 = blockIdx.x * 128;
  int rA = lane >> 2, cA = (lane & 3) * 8;
  f32x4 acc[4][4] = {};
  for (int kt = 0; kt < K; kt += 32) {
    __syncthreads();
    #pragma unroll
    for (int c = 0; c < 2; ++c) {
      int q = w * 2 + c;
      const ushortT* ga = A + (size_t)(m0 + q * 16 + rA) * lda + kt + cA;
      const ushortT* gb = B + (size_t)(n0 + q * 16 + rA) * ldb + kt + cA;
      gload_lds16(ga, &sAt[q * 512]);
      gload_lds16(gb, &sBt[q * 512]);
    }
    __syncthreads();
    int fr = lane & 15, kk = (lane >> 4) * 8;
    bf16x8 af[4], bfr[4];
    #pragma unroll
    for (int i = 0; i < 4; ++i)
      af[i] = *(const bf16x8*)&sAt[(wm * 64 + i * 16 + fr) * 32 + kk];
    #pragma unroll
    for (int j = 0; j < 4; ++j)
      bfr[j] = *(const bf16x8*)&sBt[(wn * 64 + j * 16 + fr) * 32 + kk];
    #pragma unroll
    for (int i = 0; i < 4; ++i)
      #pragma unroll
      for (int j = 0; j < 4; ++j)
        acc[i][j] = __builtin_amdgcn_mfma_f32_16x16x32_bf16(af[i], bfr[j], acc[i][j], 0, 0, 0);
  }
  int cr = (lane >> 4) * 4, cc = lane & 15;
  #pragma unroll
  for (int i = 0; i < 4; ++i)
    #pragma unroll
    for (int j = 0; j < 4; ++j) {
      float* Cp = C + (size_t)(m0 + wm * 64 + i * 16 + cr) * ldc + (n0 + wn * 64 + j * 16 + cc);
      #pragma unroll
      for (int r = 0; r < 4; ++r) Cp[(size_t)r * ldc] = acc[i][j][r];
    }
}

// ---------------- conv(K=4 causal, depthwise) + silu + dt/logdA precompute ----------------
__global__ __launch_bounds__(256) void conv_dt_kernel(const float* __restrict__ zx,
    const float* __restrict__ cwf, const float* __restrict__ cbf,
    const float* __restrict__ cwb, const float* __restrict__ cbb,
    const float* __restrict__ dtbf, const float* __restrict__ alogf,
    const float* __restrict__ dtbb, const float* __restrict__ alogb,
    float* __restrict__ xconv, float* __restrict__ dts, float* __restrict__ lda_) {
  int bid = blockIdx.x;
  int dir = bid >> 11, row = bid & 2047;
  int t = row & 1023;
  const float* cw   = dir ? cwb : cwf;
  const float* cb   = dir ? cbb : cbf;
  const float* dtb  = dir ? dtbb : dtbf;
  const float* alog = dir ? alogb : alogf;
  const float* zrow = zx + (size_t)bid * NP1;
  int tid = threadIdx.x;
  if (tid < HH) {
    float raw = zrow[3200 + tid] + dtb[tid];
    float dtv = raw > 20.f ? raw : log1pf(expf(raw));
    dts[(size_t)bid * HH + tid] = dtv;
    lda_[(size_t)bid * HH + tid] = -expf(alog[tid]) * dtv;   // log dA (negative)
  }
  float* xrow = xconv + (size_t)bid * CONVD;
  for (int c = tid; c < CONVD; c += 256) {
    float acc = cb[c];
    #pragma unroll
    for (int k = 0; k < 4; ++k) {
      int tt = t - 3 + k;
      if (tt >= 0) acc += zrow[(long)(k - 3) * NP1 + 1536 + c] * cw[c * 4 + k];
    }
    xrow[c] = acc / (1.f + expf(-acc));
  }
}

// ---------------- pass 1 (SSD form): block per (gh, chunk) ----------------
// G = C.B^T (MFMA); M = G * decay; Y_intra = M.X (MFMA); S_loc = (w*B)^T.X (MFMA).
// Writes: Y_intra, S_loc [n][p], per-t cw = exp(cumsum logdA).
__global__ __launch_bounds__(256) void ssd_chunk_kernel(const float* __restrict__ xconv,
    const float* __restrict__ dts, const float* __restrict__ lda_,
    float* __restrict__ y, float* __restrict__ sloc, float* __restrict__ cwg) {
  __shared__ ushortT sCb[4096];   // [t][n]
  __shared__ ushortT sBb[4096];   // [s][n]
  __shared__ ushortT sBT[4096];   // [n][t]  (weighted)
  __shared__ ushortT sXT[4096];   // [p][t]
  __shared__ ushortT sMb[4096];   // [t][s]
  __shared__ float clog[64];
  __shared__ float dt64[64];
  __shared__ float wv64[64];
  int gh = blockIdx.x;                 // dir*48 + b*24 + h
  int c  = blockIdx.y;                 // chunk
  int dir = gh / 48;
  int rem = gh % 48;
  int b = rem / 24, h = rem % 24;
  int tid = threadIdx.x, lane = tid & 63;
  int w = tid >> 6;
  size_t rowbase = ((size_t)dir * 2 + b) * 1024;
  size_t trow = rowbase + (size_t)c * CLEN;

  // ---- phase 1: stage C, B, X^T; wave0 computes clog / wv / cw ----
  #pragma unroll
  for (int it = 0; it < 16; ++it) {
    int idx = it * 256 + tid;
    int r = idx >> 6, cc = idx & 63;
    const float* xrow = xconv + (trow + r) * CONVD;
    sCb[SWZ(r, cc)] = f2bf(xrow[1600 + cc]);
    sBb[SWZ(r, cc)] = f2bf(xrow[1536 + cc]);
    sXT[SWZ(cc, r)] = f2bf(xrow[h * 64 + cc]);   // transpose: [p][t]
  }
  if (tid < 64) {
    float ld = lda_[(trow + tid) * HH + h];
    float dtv = dts[(trow + tid) * HH + h];
    float v = ld;
    #pragma unroll
    for (int o = 1; o < 64; o <<= 1) {
      float u = __shfl_up(v, o, 64);
      if (tid >= o) v += u;
    }
    float tot = __shfl(v, 63, 64);
    clog[tid] = v;
    dt64[tid] = dtv;
    wv64[tid] = dtv * __expf(tot - v);
    cwg[(trow + tid) * HH + h] = __expf(v);
  }
  __syncthreads();

  int fr = lane & 15, kq = lane >> 4;

  // ---- phase 2: build weighted B^T; G = C.B^T; decay -> M(bf16) ----
  #pragma unroll
  for (int it = 0; it < 16; ++it) {
    int idx = it * 256 + tid;
    int s = idx >> 6, n = idx & 63;
    float bv = bf2f(sBb[SWZ(s, n)]) * wv64[s];
    sBT[SWZ(n, s)] = f2bf(bv);
  }
  f32x4 accG[4] = {};
  #pragma unroll
  for (int kt = 0; kt < 2; ++kt) {
    int kk = kt * 32 + kq * 8;
    bf16x8 af = *(const bf16x8*)&sCb[SWZ(w * 16 + fr, kk)];
    #pragma unroll
    for (int j = 0; j < 4; ++j) {
      bf16x8 bf_ = *(const bf16x8*)&sBb[SWZ(j * 16 + fr, kk)];
      accG[j] = __builtin_amdgcn_mfma_f32_16x16x32_bf16(af, bf_, accG[j], 0, 0, 0);
    }
  }
  #pragma unroll
  for (int j = 0; j < 4; ++j) {
    int s = j * 16 + fr;
    float cls = clog[s], dtv = dt64[s];
    #pragma unroll
    for (int r = 0; r < 4; ++r) {
      int t = w * 16 + kq * 4 + r;
      float dec = (s <= t) ? __expf(clog[t] - cls) * dtv : 0.f;
      sMb[SWZ(t, s)] = f2bf(accG[j][r] * dec);
    }
  }
  __syncthreads();

  // ---- phase 3: Y = M.X^T-op ; S = wB^T.X^T-op (shared B-fragments) ----
  f32x4 accY[4] = {}, accS[4] = {};
  #pragma unroll
  for (int kt = 0; kt < 2; ++kt) {
    int kk = kt * 32 + kq * 8;
    bf16x8 aM = *(const bf16x8*)&sMb[SWZ(w * 16 + fr, kk)];
    bf16x8 aB = *(const bf16x8*)&sBT[SWZ(w * 16 + fr, kk)];
    #pragma unroll
    for (int j = 0; j < 4; ++j) {
      bf16x8 bx = *(const bf16x8*)&sXT[SWZ(j * 16 + fr, kk)];
      accY[j] = __builtin_amdgcn_mfma_f32_16x16x32_bf16(aM, bx, accY[j], 0, 0, 0);
      accS[j] = __builtin_amdgcn_mfma_f32_16x16x32_bf16(aB, bx, accS[j], 0, 0, 0);
    }
  }
  float* sp = sloc + ((size_t)gh * NCHUNK + c) * 4096;
  #pragma unroll
  for (int j = 0; j < 4; ++j) {
    #pragma unroll
    for (int r = 0; r < 4; ++r) {
      int t = w * 16 + kq * 4 + r;        // row (t for Y, n for S)
      int p = j * 16 + fr;                // col
      y[(trow + t) * DI + h * 64 + p] = accY[j][r];
      sp[t * 64 + p] = accS[j][r];
    }
  }
}

// ---------------- pass 2: serial prefix over chunk states (96 blocks) ----------------
__global__ __launch_bounds__(256) void chunk_prefix_kernel(float* __restrict__ sloc,
    const float* __restrict__ cwb_) {
  int gh = blockIdx.x;
  int dir = gh / 48;
  int rem = gh % 48;
  int b = rem / 24, h = rem % 24;
  int tid = threadIdx.x;
  size_t rowbase = ((size_t)dir * 2 + b) * 1024;
  float R[16];
  #pragma unroll
  for (int j = 0; j < 16; ++j) R[j] = 0.f;
  for (int c = 1; c < NCHUNK; ++c) {
    float W = cwb_[(rowbase + (size_t)c * CLEN - 1) * HH + h];
    float* slot = sloc + ((size_t)gh * NCHUNK + (c - 1)) * 4096;
    #pragma unroll
    for (int j = 0; j < 16; ++j) {
      float Lv = slot[j * 256 + tid];
      R[j] = __builtin_fmaf(R[j], W, Lv);
      slot[j * 256 + tid] = R[j];
    }
  }
}

// ---------------- pass 3: y[t] += cw[t] * C_t . S_init  (chunks 1..15) ----------------
__global__ __launch_bounds__(256) void fixup_kernel(const float* __restrict__ xconv,
    const float* __restrict__ cwb_, const float* __restrict__ sloc,
    float* __restrict__ y) {
  __shared__ float sS[4096];   // [n][p]
  __shared__ float sC[4096];   // [t][n]
  int gh = blockIdx.x;
  int c = blockIdx.y + 1;      // 1..15
  int dir = gh / 48;
  int rem = gh % 48;
  int b = rem / 24, h = rem % 24;
  int tid = threadIdx.x, lane = tid & 63;
  int w = tid >> 6;
  size_t rowbase = ((size_t)dir * 2 + b) * 1024;
  const float* slot = sloc + ((size_t)gh * NCHUNK + (c - 1)) * 4096;
  #pragma unroll
  for (int j = 0; j < 16; ++j) sS[j * 256 + tid] = slot[j * 256 + tid];
  for (int idx = tid; idx < 4096; idx += 256) {
    int tl = idx >> 6, n = idx & 63;
    sC[idx] = xconv[(rowbase + c * CLEN + tl) * CONVD + 1600 + n];
  }
  __syncthreads();
  #pragma unroll
  for (int k = 0; k < 16; ++k) {
    int tl = w * 16 + k;
    int t = c * CLEN + tl;
    float acc = 0.f;
    #pragma unroll 8
    for (int n = 0; n < 64; ++n)
      acc = __builtin_fmaf(sC[tl * 64 + n], sS[n * 64 + lane], acc);
    size_t yi = (rowbase + t) * DI + h * 64 + lane;
    float cwv = cwb_[(rowbase + t) * HH + h];
    y[yi] = __builtin_fmaf(cwv, acc, y[yi]);
  }
}

// ---------------- +D*xs, gate silu(z), RMSNorm, -> bf16 ----------------
__global__ __launch_bounds__(256) void gate_norm_kernel(const float* __restrict__ y,
    const float* __restrict__ zx, const float* __restrict__ xconv,
    const float* __restrict__ Df, const float* __restrict__ Db,
    const float* __restrict__ nwf, const float* __restrict__ nwb,
    ushortT* __restrict__ yn) {
  __shared__ float lds[4];
  int bid = blockIdx.x;
  int dir = bid >> 11;
  const float* Dp = dir ? Db : Df;
  const float* nw = dir ? nwb : nwf;
  const float* yr = y + (size_t)bid * DI;
  const float* zr = zx + (size_t)bid * NP1;
  const float* xcr = xconv + (size_t)bid * CONVD;
  int tid = threadIdx.x;
  float vals[6];
  float ss = 0.f;
  #pragma unroll
  for (int i = 0; i < 6; ++i) {
    int c = i * 256 + tid;
    float yv = yr[c] + Dp[c >> 6] * xcr[c];
    float zv = zr[c];
    yv *= zv / (1.f + expf(-zv));
    vals[i] = yv;
    ss += yv * yv;
  }
  #pragma unroll
  for (int o = 32; o; o >>= 1) ss += __shfl_xor(ss, o, 64);
  if ((tid & 63) == 0) lds[tid >> 6] = ss;
  __syncthreads();
  float ms = (lds[0] + lds[1] + lds[2] + lds[3]) * (1.f / 1536.f);
  float sc = rsqrtf(ms + EPSF);
  ushortT* orow = yn + (size_t)bid * DI;
  #pragma unroll
  for (int i = 0; i < 6; ++i) {
    int c = i * 256 + tid;
    orow[c] = f2bf(vals[i] * sc * nw[c]);
  }
}

// ---------------- out[t] = 2x[t] + mf[t] + mb[SEQ[t]] ----------------
__global__ __launch_bounds__(256) void combine_kernel(const float* __restrict__ x,
    const float* __restrict__ mf, const float* __restrict__ mb,
    float* __restrict__ out) {
  int bid = blockIdx.x;   // b*1024 + t
  int b = bid >> 10, t = bid & 1023;
  int st = seqmap(t);
  const float* xr = x + (size_t)bid * DM;
  const float* fr = mf + (size_t)bid * DM;
  const float* br = mb + (size_t)(b * 1024 + st) * DM;
  float* orow = out + (size_t)bid * DM;
  for (int c = threadIdx.x; c < DM; c += 256)
    orow[c] = 2.f * xr[c] + fr[c] + br[c];
}

extern "C" void kernel_launch(void* const* d_in, const int* in_sizes, int n_in,
                              void* d_out, int out_size, void* d_ws, size_t ws_size,
                              hipStream_t stream) {
  const float* x       = (const float*)d_in[0];
  const float* f_ln_w  = (const float*)d_in[1];
  const float* f_ln_b  = (const float*)d_in[2];
  const float* f_in_w  = (const float*)d_in[3];
  const float* f_cw    = (const float*)d_in[4];
  const float* f_cb    = (const float*)d_in[5];
  const float* f_dtb   = (const float*)d_in[6];
  const float* f_alog  = (const float*)d_in[7];
  const float* f_D     = (const float*)d_in[8];
  const float* f_nw    = (const float*)d_in[9];
  const float* f_ow    = (const float*)d_in[10];
  const float* b_ln_w  = (const float*)d_in[11];
  const float* b_ln_b  = (const float*)d_in[12];
  const float* b_in_w  = (const float*)d_in[13];
  const float* b_cw    = (const float*)d_in[14];
  const float* b_cb    = (const float*)d_in[15];
  const float* b_dtb   = (const float*)d_in[16];
  const float* b_alog  = (const float*)d_in[17];
  const float* b_D     = (const float*)d_in[18];
  const float* b_nw    = (const float*)d_in[19];
  const float* b_ow    = (const float*)d_in[20];

  char* ws = (char*)d_ws;
  size_t off = 0;
  auto carve = [&](size_t bytes) -> char* {
    off = (off + 255) & ~(size_t)255;
    char* p = ws + off;
    off += bytes;
    return p;
  };
  ushortT* XLN  = (ushortT*)carve((size_t)2 * ROWS * DM * 2);
  ushortT* WP1  = (ushortT*)carve((size_t)2 * NP1 * DM * 2);
  ushortT* W2   = (ushortT*)carve((size_t)2 * DM * DI * 2);
  float*   ZX   = (float*)carve((size_t)2 * ROWS * NP1 * 4);
  float*   XC   = (float*)carve((size_t)2 * ROWS * CONVD * 4);
  float*   DTS  = (float*)carve((size_t)2 * ROWS * HH * 4);
  float*   LDA  = (float*)carve((size_t)2 * ROWS * HH * 4);
  float*   Y    = (float*)carve((size_t)2 * ROWS * DI * 4);
  ushortT* YN   = (ushortT*)carve((size_t)2 * ROWS * DI * 2);
  float*   MOUT = (float*)carve((size_t)2 * ROWS * DM * 4);
  float*   SLOC = (float*)carve((size_t)96 * NCHUNK * 4096 * 4);
  float*   CW   = (float*)carve((size_t)2 * ROWS * HH * 4);

  // weight conversion (merged)
  cvt_all_kernel<<<2048, 256, 0, stream>>>(f_in_w, b_in_w, f_ow, b_ow, WP1, W2);

  // layernorm (both dirs)
  ln_kernel<<<4096, 256, 0, stream>>>(x, f_ln_w, f_ln_b, b_ln_w, b_ln_b, XLN);

  // in_proj: [2048,768] x [3328,768]^T -> [2048,3328]
  gemm_bf16<<<dim3(NP1 / 128, ROWS / 128, 2), 256, 0, stream>>>(
      XLN, WP1, ZX, DM, DM, DM, NP1,
      (long)ROWS * DM, (long)NP1 * DM, (long)ROWS * NP1);

  // conv + dt/logdA
  conv_dt_kernel<<<4096, 256, 0, stream>>>(ZX, f_cw, f_cb, b_cw, b_cb,
                                           f_dtb, f_alog, b_dtb, b_alog,
                                           XC, DTS, LDA);

  // chunked scan: pass 1 (SSD/MFMA), pass 2 (chunk-state prefix), pass 3 (fixup)
  ssd_chunk_kernel<<<dim3(96, NCHUNK), 256, 0, stream>>>(XC, DTS, LDA, Y, SLOC, CW);
  chunk_prefix_kernel<<<96, 256, 0, stream>>>(SLOC, CW);
  fixup_kernel<<<dim3(96, NCHUNK - 1), 256, 0, stream>>>(XC, CW, SLOC, Y);

  // gate + rmsnorm
  gate_norm_kernel<<<4096, 256, 0, stream>>>(Y, ZX, XC, f_D, b_D, f_nw, b_nw, YN);

  // out_proj: [2048,1536] x [768,1536]^T -> [2048,768]
  gemm_bf16<<<dim3(DM / 128, ROWS / 128, 2), 256, 0, stream>>>(
      YN, W2, MOUT, DI, DI, DI, DM,
      (long)ROWS * DI, (long)DM * DI, (long)ROWS * DM);

  // combine
  combine_kernel<<<2048, 256, 0, stream>>>(x, MOUT, MOUT + (size_t)ROWS * DM, (float*)d_out);
}

// Round 4
// 193.362 us; speedup vs baseline: 3.1618x; 1.1688x over previous
//
#include <hip/hip_runtime.h>
#include <cstdint>

#define DM    768
#define DI    1536
#define PP    64
#define HH    24
#define NN    64
#define CONVD 1664
#define DINP  3224
#define NP1   3328   // 3224 padded to 26*128
#define LL    1024
#define ROWS  2048   // BATCH*LL
#define EPSF  1e-5f
#define NCHUNK 16
#define CLEN   64

typedef unsigned short ushortT;
typedef __attribute__((ext_vector_type(8))) __bf16 bf16x8;
typedef __attribute__((ext_vector_type(8))) unsigned short ushort8;
typedef __attribute__((ext_vector_type(4))) float f32x4;

__device__ __forceinline__ int seqmap(int t) { return 1023 - 32 * (t & 31) - (t >> 5); }

__device__ __forceinline__ ushortT f2bf(float f) {
  union { float f; unsigned u; } v; v.f = f;
  unsigned r = v.u + 0x7FFF + ((v.u >> 16) & 1);
  return (ushortT)(r >> 16);
}
__device__ __forceinline__ float bf2f(ushortT b) {
  union { unsigned u; float f; } v; v.u = ((unsigned)b) << 16;
  return v.f;
}

__device__ __forceinline__ void gload_lds16(const void* g, void* l) {
  __builtin_amdgcn_global_load_lds((const __attribute__((address_space(1))) void*)g,
                                   (__attribute__((address_space(3))) void*)l, 16, 0, 0);
}

// swizzled ushort index into a 64x64 bf16 tile (row stride 64): T2 XOR swizzle
#define SWZ(r, c) ((r) * 64 + ((c) ^ (((r) & 7) << 3)))

// ---------------- merged weight convert (f32 -> bf16, zero-pad tail) ----------------
__global__ __launch_bounds__(256) void cvt_all_kernel(
    const float* __restrict__ fw1, const float* __restrict__ bw1,
    const float* __restrict__ fw2, const float* __restrict__ bw2,
    ushortT* __restrict__ WP1, ushortT* __restrict__ W2) {
  const long NW1 = (long)NP1 * DM, SW1 = (long)DINP * DM, NW2 = (long)DM * DI;
  const long total = 2 * NW1 + 2 * NW2;
  for (long i = (long)blockIdx.x * 256 + threadIdx.x; i < total; i += (long)gridDim.x * 256) {
    if (i < NW1) {
      WP1[i] = (i < SW1) ? f2bf(fw1[i]) : (ushortT)0;
    } else if (i < 2 * NW1) {
      long j = i - NW1;
      WP1[i] = (j < SW1) ? f2bf(bw1[j]) : (ushortT)0;
    } else if (i < 2 * NW1 + NW2) {
      long j = i - 2 * NW1;
      W2[j] = f2bf(fw2[j]);
    } else {
      long j = i - 2 * NW1 - NW2;
      W2[NW2 + j] = f2bf(bw2[j]);
    }
  }
}

// ---------------- LayerNorm (both dirs; dir1 gathers via SEQ) ----------------
__global__ __launch_bounds__(256) void ln_kernel(const float* __restrict__ x,
    const float* __restrict__ wf, const float* __restrict__ bf_,
    const float* __restrict__ wb, const float* __restrict__ bb,
    ushortT* __restrict__ xln) {
  __shared__ float lds[4];
  int bid = blockIdx.x;
  int dir = bid >> 11, row = bid & 2047;
  int b = row >> 10, t = row & 1023;
  int st = dir ? seqmap(t) : t;
  const float* xr = x + (size_t)(b * 1024 + st) * DM;
  const float* w = dir ? wb : wf;
  const float* bia = dir ? bb : bf_;
  int tid = threadIdx.x;
  float v0 = xr[tid], v1 = xr[tid + 256], v2 = xr[tid + 512];
  float s = v0 + v1 + v2;
  #pragma unroll
  for (int o = 32; o; o >>= 1) s += __shfl_xor(s, o, 64);
  if ((tid & 63) == 0) lds[tid >> 6] = s;
  __syncthreads();
  float mean = (lds[0] + lds[1] + lds[2] + lds[3]) * (1.f / 768.f);
  __syncthreads();
  float d0 = v0 - mean, d1 = v1 - mean, d2 = v2 - mean;
  float q = d0 * d0 + d1 * d1 + d2 * d2;
  #pragma unroll
  for (int o = 32; o; o >>= 1) q += __shfl_xor(q, o, 64);
  if ((tid & 63) == 0) lds[tid >> 6] = q;
  __syncthreads();
  float var = (lds[0] + lds[1] + lds[2] + lds[3]) * (1.f / 768.f);
  float rs = rsqrtf(var + EPSF);
  ushortT* orow = xln + (size_t)bid * DM;
  orow[tid]       = f2bf(d0 * rs * w[tid]       + bia[tid]);
  orow[tid + 256] = f2bf(d1 * rs * w[tid + 256] + bia[tid + 256]);
  orow[tid + 512] = f2bf(d2 * rs * w[tid + 512] + bia[tid + 512]);
}

// ---------------- bf16 MFMA GEMM: C[M,N] = A[M,K] * B[N,K]^T ----------------
// MODE 0: f32 output to Cf. MODE 1: bf16 output to Cb for n0<3200, f32 to Cf (dt tail, ld 128).
template<int MODE>
__global__ __launch_bounds__(256) void gemm_bf16(
    const ushortT* __restrict__ Aall, const ushortT* __restrict__ Ball,
    float* __restrict__ Cfall, ushortT* __restrict__ Cball,
    int K, int lda, int ldb, int ldc, long sA, long sB, long sCf, long sCb) {
  __shared__ ushortT sAt[128 * 32];
  __shared__ ushortT sBt[128 * 32];
  const ushortT* A = Aall + (size_t)blockIdx.z * sA;
  const ushortT* B = Ball + (size_t)blockIdx.z * sB;
  int tid = threadIdx.x, lane = tid & 63, w = tid >> 6;
  int wm = w >> 1, wn = w & 1;
  int m0 = blockIdx.y * 128, n0 = blockIdx.x * 128;
  int rA = lane >> 2, cA = (lane & 3) * 8;
  f32x4 acc[4][4] = {};
  for (int kt = 0; kt < K; kt += 32) {
    __syncthreads();
    #pragma unroll
    for (int c = 0; c < 2; ++c) {
      int q = w * 2 + c;
      const ushortT* ga = A + (size_t)(m0 + q * 16 + rA) * lda + kt + cA;
      const ushortT* gb = B + (size_t)(n0 + q * 16 + rA) * ldb + kt + cA;
      gload_lds16(ga, &sAt[q * 512]);
      gload_lds16(gb, &sBt[q * 512]);
    }
    __syncthreads();
    int fr = lane & 15, kk = (lane >> 4) * 8;
    bf16x8 af[4], bfr[4];
    #pragma unroll
    for (int i = 0; i < 4; ++i)
      af[i] = *(const bf16x8*)&sAt[(wm * 64 + i * 16 + fr) * 32 + kk];
    #pragma unroll
    for (int j = 0; j < 4; ++j)
      bfr[j] = *(const bf16x8*)&sBt[(wn * 64 + j * 16 + fr) * 32 + kk];
    #pragma unroll
    for (int i = 0; i < 4; ++i)
      #pragma unroll
      for (int j = 0; j < 4; ++j)
        acc[i][j] = __builtin_amdgcn_mfma_f32_16x16x32_bf16(af[i], bfr[j], acc[i][j], 0, 0, 0);
  }
  int cr = (lane >> 4) * 4, cc = lane & 15;
  if (MODE == 0 || n0 >= 3200) {
    int ldo = (MODE == 0) ? ldc : 128;
    int nb  = (MODE == 0) ? n0 : 0;
    float* Cf = Cfall + (size_t)blockIdx.z * sCf;
    #pragma unroll
    for (int i = 0; i < 4; ++i)
      #pragma unroll
      for (int j = 0; j < 4; ++j) {
        float* Cp = Cf + (size_t)(m0 + wm * 64 + i * 16 + cr) * ldo + (nb + wn * 64 + j * 16 + cc);
        #pragma unroll
        for (int r = 0; r < 4; ++r) Cp[(size_t)r * ldo] = acc[i][j][r];
      }
  } else {
    ushortT* Cb = Cball + (size_t)blockIdx.z * sCb;
    #pragma unroll
    for (int i = 0; i < 4; ++i)
      #pragma unroll
      for (int j = 0; j < 4; ++j) {
        ushortT* Cp = Cb + (size_t)(m0 + wm * 64 + i * 16 + cr) * ldc + (n0 + wn * 64 + j * 16 + cc);
        #pragma unroll
        for (int r = 0; r < 4; ++r) Cp[(size_t)r * ldc] = f2bf(acc[i][j][r]);
      }
  }
}

// ---------------- conv(K=4 causal, depthwise) + silu + dt/logdA precompute ----------------
__global__ __launch_bounds__(256) void conv_dt_kernel(const ushortT* __restrict__ zxb,
    const float* __restrict__ dtt,
    const float* __restrict__ cwf, const float* __restrict__ cbf,
    const float* __restrict__ cwb, const float* __restrict__ cbb,
    const float* __restrict__ dtbf, const float* __restrict__ alogf,
    const float* __restrict__ dtbb, const float* __restrict__ alogb,
    ushortT* __restrict__ xcb, float* __restrict__ dts, float* __restrict__ lda_) {
  int bid = blockIdx.x;
  int dir = bid >> 11, row = bid & 2047;
  int t = row & 1023;
  const float* cw   = dir ? cwb : cwf;
  const float* cb   = dir ? cbb : cbf;
  const float* dtb  = dir ? dtbb : dtbf;
  const float* alog = dir ? alogb : alogf;
  const ushortT* zrow = zxb + (size_t)bid * NP1;
  int tid = threadIdx.x;
  if (tid < HH) {
    float raw = dtt[(size_t)bid * 128 + tid] + dtb[tid];
    float dtv = raw > 20.f ? raw : log1pf(expf(raw));
    dts[(size_t)bid * HH + tid] = dtv;
    lda_[(size_t)bid * HH + tid] = -expf(alog[tid]) * dtv;   // log dA (negative)
  }
  ushortT* xrow = xcb + (size_t)bid * CONVD;
  for (int c = tid; c < CONVD; c += 256) {
    float acc = cb[c];
    #pragma unroll
    for (int k = 0; k < 4; ++k) {
      int tt = t - 3 + k;
      if (tt >= 0) acc += bf2f(zrow[(long)(k - 3) * NP1 + 1536 + c]) * cw[c * 4 + k];
    }
    xrow[c] = f2bf(acc / (1.f + expf(-acc)));
  }
}

// ---------------- pass 1 (SSD form): block per (gh, chunk) ----------------
// G = C.B^T (MFMA); M = G*decay; Y_intra = M.X (MFMA); S_loc = (wB)^T.X (MFMA).
// Writes: Y_intra bf16, S_loc bf16 [n][p], cw = exp(cumsum logdA), C tile (h==0 only).
__global__ __launch_bounds__(256) void ssd_chunk_kernel(const ushortT* __restrict__ xcb,
    const float* __restrict__ dts, const float* __restrict__ lda_,
    ushortT* __restrict__ yb, ushortT* __restrict__ slocb, float* __restrict__ cwg,
    ushortT* __restrict__ cbg) {
  __shared__ ushortT sCb[4096];   // [t][n]
  __shared__ ushortT sBb[4096];   // [s][n]
  __shared__ ushortT sBT[4096];   // [n][t]  (weighted)
  __shared__ ushortT sXT[4096];   // [p][t]
  __shared__ ushortT sMb[4096];   // [t][s]
  __shared__ float clog[64];
  __shared__ float dt64[64];
  __shared__ float wv64[64];
  int gh = blockIdx.x;                 // dir*48 + b*24 + h
  int c  = blockIdx.y;                 // chunk
  int dir = gh / 48;
  int rem = gh % 48;
  int b = rem / 24, h = rem % 24;
  int tid = threadIdx.x, lane = tid & 63;
  int w = tid >> 6;
  size_t rowbase = ((size_t)dir * 2 + b) * 1024;
  size_t trow = rowbase + (size_t)c * CLEN;

  // ---- phase 1: stage C, B (ushort8), X^T (scalar transpose) ----
  #pragma unroll
  for (int it2 = 0; it2 < 2; ++it2) {
    int idx2 = it2 * 256 + tid;
    int r = idx2 >> 3, c8 = (idx2 & 7) << 3;
    const ushortT* xrow = xcb + (trow + r) * CONVD;
    *(ushort8*)&sCb[SWZ(r, c8)] = *(const ushort8*)&xrow[1600 + c8];
    *(ushort8*)&sBb[SWZ(r, c8)] = *(const ushort8*)&xrow[1536 + c8];
  }
  #pragma unroll
  for (int it = 0; it < 16; ++it) {
    int idx = it * 256 + tid;
    int r = idx >> 6, cc = idx & 63;
    sXT[SWZ(cc, r)] = xcb[(trow + r) * CONVD + h * 64 + cc];
  }
  if (tid < 64) {
    float ld = lda_[(trow + tid) * HH + h];
    float dtv = dts[(trow + tid) * HH + h];
    float v = ld;
    #pragma unroll
    for (int o = 1; o < 64; o <<= 1) {
      float u = __shfl_up(v, o, 64);
      if (tid >= o) v += u;
    }
    float tot = __shfl(v, 63, 64);
    clog[tid] = v;
    dt64[tid] = dtv;
    wv64[tid] = dtv * __expf(tot - v);
    cwg[(trow + tid) * HH + h] = __expf(v);
  }
  __syncthreads();

  // dump C tile once per (dir,b,chunk) for the fixup pass
  if (h == 0) {
    ushortT* dst = cbg + ((size_t)((dir * 2 + b) * NCHUNK + c)) * 4096;
    for (int idx = tid; idx < 4096; idx += 256) dst[idx] = sCb[idx];
  }

  int fr = lane & 15, kq = lane >> 4;

  // ---- phase 2: weighted B^T; G = C.B^T; decay -> M(bf16) ----
  #pragma unroll
  for (int it = 0; it < 16; ++it) {
    int idx = it * 256 + tid;
    int s = idx >> 6, n = idx & 63;
    float bv = bf2f(sBb[SWZ(s, n)]) * wv64[s];
    sBT[SWZ(n, s)] = f2bf(bv);
  }
  f32x4 accG[4] = {};
  #pragma unroll
  for (int kt = 0; kt < 2; ++kt) {
    int kk = kt * 32 + kq * 8;
    bf16x8 af = *(const bf16x8*)&sCb[SWZ(w * 16 + fr, kk)];
    #pragma unroll
    for (int j = 0; j < 4; ++j) {
      bf16x8 bf_ = *(const bf16x8*)&sBb[SWZ(j * 16 + fr, kk)];
      accG[j] = __builtin_amdgcn_mfma_f32_16x16x32_bf16(af, bf_, accG[j], 0, 0, 0);
    }
  }
  #pragma unroll
  for (int j = 0; j < 4; ++j) {
    int s = j * 16 + fr;
    float cls = clog[s], dtv = dt64[s];
    #pragma unroll
    for (int r = 0; r < 4; ++r) {
      int t = w * 16 + kq * 4 + r;
      float dec = (s <= t) ? __expf(clog[t] - cls) * dtv : 0.f;
      sMb[SWZ(t, s)] = f2bf(accG[j][r] * dec);
    }
  }
  __syncthreads();

  // ---- phase 3: Y = M.X ; S = wB^T.X (shared X fragments) ----
  f32x4 accY[4] = {}, accS[4] = {};
  #pragma unroll
  for (int kt = 0; kt < 2; ++kt) {
    int kk = kt * 32 + kq * 8;
    bf16x8 aM = *(const bf16x8*)&sMb[SWZ(w * 16 + fr, kk)];
    bf16x8 aB = *(const bf16x8*)&sBT[SWZ(w * 16 + fr, kk)];
    #pragma unroll
    for (int j = 0; j < 4; ++j) {
      bf16x8 bx = *(const bf16x8*)&sXT[SWZ(j * 16 + fr, kk)];
      accY[j] = __builtin_amdgcn_mfma_f32_16x16x32_bf16(aM, bx, accY[j], 0, 0, 0);
      accS[j] = __builtin_amdgcn_mfma_f32_16x16x32_bf16(aB, bx, accS[j], 0, 0, 0);
    }
  }
  ushortT* spb = slocb + ((size_t)gh * NCHUNK + c) * 4096;
  #pragma unroll
  for (int j = 0; j < 4; ++j) {
    #pragma unroll
    for (int r = 0; r < 4; ++r) {
      int t = w * 16 + kq * 4 + r;        // row (t for Y, n for S)
      int p = j * 16 + fr;                // col
      yb[(trow + t) * DI + h * 64 + p] = f2bf(accY[j][r]);
      spb[t * 64 + p] = f2bf(accS[j][r]);
    }
  }
}

// ---------------- pass 2: serial prefix over chunk states (96 blocks) ----------------
// Reads local states bf16; writes S_init for chunk c at slot c-1: transposed [p][n],
// XOR-swizzled, bf16 (ready for linear global_load_lds in fixup).
__global__ __launch_bounds__(256) void chunk_prefix_kernel(
    const ushortT* __restrict__ slocb, const float* __restrict__ cwg,
    ushortT* __restrict__ sinitb) {
  __shared__ float ldsT[64 * 65];
  int gh = blockIdx.x;
  int dir = gh / 48;
  int rem = gh % 48;
  int b = rem / 24, h = rem % 24;
  int tid = threadIdx.x;
  size_t rowbase = ((size_t)dir * 2 + b) * 1024;
  float R[16];
  #pragma unroll
  for (int j = 0; j < 16; ++j) R[j] = 0.f;
  for (int c = 1; c < NCHUNK; ++c) {
    float W = cwg[(rowbase + (size_t)c * CLEN - 1) * HH + h];
    const ushortT* slot = slocb + ((size_t)gh * NCHUNK + (c - 1)) * 4096;
    #pragma unroll
    for (int j = 0; j < 16; ++j) {
      int idx = j * 256 + tid, n = idx >> 6, p = idx & 63;
      R[j] = __builtin_fmaf(R[j], W, bf2f(slot[idx]));
      ldsT[n * 65 + p] = R[j];
    }
    __syncthreads();
    ushortT* outp = sinitb + ((size_t)gh * (NCHUNK - 1) + (c - 1)) * 4096;
    #pragma unroll
    for (int j = 0; j < 16; ++j) {
      int idx = j * 256 + tid, p = idx >> 6, n = idx & 63;
      outp[SWZ(p, n)] = f2bf(ldsT[n * 65 + p]);
    }
    __syncthreads();
  }
}

// ---------------- pass 3 (MFMA): YI[t,p] = cw[t] * (C_t . S_init) ----------------
__global__ __launch_bounds__(256) void fixup_kernel(
    const ushortT* __restrict__ cbg, const ushortT* __restrict__ sinitb,
    const float* __restrict__ cwg, ushortT* __restrict__ yib) {
  __shared__ ushortT sCb[4096];
  __shared__ ushortT sST[4096];
  int gh = blockIdx.x;
  int c = blockIdx.y + 1;      // 1..15
  int dir = gh / 48;
  int rem = gh % 48;
  int b = rem / 24, h = rem % 24;
  int tid = threadIdx.x, lane = tid & 63, w = tid >> 6;
  size_t rowbase = ((size_t)dir * 2 + b) * 1024;
  size_t trow = rowbase + (size_t)c * CLEN;
  const ushortT* cbSrc = cbg + ((size_t)((dir * 2 + b) * NCHUNK + c)) * 4096;
  const ushortT* stSrc = sinitb + ((size_t)gh * (NCHUNK - 1) + (c - 1)) * 4096;
  #pragma unroll
  for (int ph = 0; ph < 2; ++ph) {
    int base = ph * 2048 + w * 512;
    gload_lds16(cbSrc + base + lane * 8, &sCb[base]);
    gload_lds16(stSrc + base + lane * 8, &sST[base]);
  }
  __syncthreads();
  int fr = lane & 15, kq = lane >> 4;
  f32x4 accY[4] = {};
  #pragma unroll
  for (int kt = 0; kt < 2; ++kt) {
    int kk = kt * 32 + kq * 8;
    bf16x8 aC = *(const bf16x8*)&sCb[SWZ(w * 16 + fr, kk)];
    #pragma unroll
    for (int j = 0; j < 4; ++j) {
      bf16x8 bS = *(const bf16x8*)&sST[SWZ(j * 16 + fr, kk)];
      accY[j] = __builtin_amdgcn_mfma_f32_16x16x32_bf16(aC, bS, accY[j], 0, 0, 0);
    }
  }
  float cwv[4];
  #pragma unroll
  for (int r = 0; r < 4; ++r)
    cwv[r] = cwg[(trow + w * 16 + kq * 4 + r) * HH + h];
  #pragma unroll
  for (int j = 0; j < 4; ++j)
    #pragma unroll
    for (int r = 0; r < 4; ++r) {
      int t = w * 16 + kq * 4 + r, p = j * 16 + fr;
      yib[(trow + t) * DI + h * 64 + p] = f2bf(accY[j][r] * cwv[r]);
    }
}

// ---------------- +D*xs, gate silu(z), RMSNorm, -> bf16 ----------------
__global__ __launch_bounds__(256) void gate_norm_kernel(
    const ushortT* __restrict__ yb, const ushortT* __restrict__ yib,
    const ushortT* __restrict__ zxb, const ushortT* __restrict__ xcb,
    const float* __restrict__ Df, const float* __restrict__ Db,
    const float* __restrict__ nwf, const float* __restrict__ nwb,
    ushortT* __restrict__ yn) {
  __shared__ float lds[4];
  int bid = blockIdx.x;            // 0..4095 (dir*2048 + b*1024 + t)
  int dir = bid >> 11;
  int t = bid & 1023;
  const float* Dp = dir ? Db : Df;
  const float* nw = dir ? nwb : nwf;
  int tid = threadIdx.x;
  bool act = tid < 192;
  int c0 = tid * 8;
  float v[8];
  float ss = 0.f;
  if (act) {
    ushort8 yv8 = *(const ushort8*)&yb[(size_t)bid * DI + c0];
    ushort8 zv8 = *(const ushort8*)&zxb[(size_t)bid * NP1 + c0];
    ushort8 xv8 = *(const ushort8*)&xcb[(size_t)bid * CONVD + c0];
    ushort8 yi8 = {};
    bool hasI = (t >= CLEN);
    if (hasI) yi8 = *(const ushort8*)&yib[(size_t)bid * DI + c0];
    float Dv = Dp[c0 >> 6];
    #pragma unroll
    for (int e = 0; e < 8; ++e) {
      float yv = bf2f(yv8[e]) + (hasI ? bf2f(yi8[e]) : 0.f) + Dv * bf2f(xv8[e]);
      float zv = bf2f(zv8[e]);
      yv *= zv / (1.f + expf(-zv));
      v[e] = yv;
      ss += yv * yv;
    }
  }
  #pragma unroll
  for (int o = 32; o; o >>= 1) ss += __shfl_xor(ss, o, 64);
  if ((tid & 63) == 0) lds[tid >> 6] = ss;
  __syncthreads();
  float ms = (lds[0] + lds[1] + lds[2] + lds[3]) * (1.f / 1536.f);
  float sc = rsqrtf(ms + EPSF);
  if (act) {
    ushort8 o8;
    #pragma unroll
    for (int e = 0; e < 8; ++e) o8[e] = f2bf(v[e] * sc * nw[c0 + e]);
    *(ushort8*)&yn[(size_t)bid * DI + c0] = o8;
  }
}

// ---------------- out[t] = 2x[t] + mf[t] + mb[SEQ[t]] ----------------
__global__ __launch_bounds__(256) void combine_kernel(const float* __restrict__ x,
    const float* __restrict__ mf, const float* __restrict__ mb,
    float* __restrict__ out) {
  int bid = blockIdx.x;   // b*1024 + t
  int b = bid >> 10, t = bid & 1023;
  int st = seqmap(t);
  int tid = threadIdx.x;
  if (tid >= 192) return;
  int c0 = tid * 4;
  const float4 xv = *(const float4*)&x[(size_t)bid * DM + c0];
  const float4 fv = *(const float4*)&mf[(size_t)bid * DM + c0];
  const float4 bv = *(const float4*)&mb[(size_t)(b * 1024 + st) * DM + c0];
  float4 o;
  o.x = 2.f * xv.x + fv.x + bv.x;
  o.y = 2.f * xv.y + fv.y + bv.y;
  o.z = 2.f * xv.z + fv.z + bv.z;
  o.w = 2.f * xv.w + fv.w + bv.w;
  *(float4*)&out[(size_t)bid * DM + c0] = o;
}

extern "C" void kernel_launch(void* const* d_in, const int* in_sizes, int n_in,
                              void* d_out, int out_size, void* d_ws, size_t ws_size,
                              hipStream_t stream) {
  const float* x       = (const float*)d_in[0];
  const float* f_ln_w  = (const float*)d_in[1];
  const float* f_ln_b  = (const float*)d_in[2];
  const float* f_in_w  = (const float*)d_in[3];
  const float* f_cw    = (const float*)d_in[4];
  const float* f_cb    = (const float*)d_in[5];
  const float* f_dtb   = (const float*)d_in[6];
  const float* f_alog  = (const float*)d_in[7];
  const float* f_D     = (const float*)d_in[8];
  const float* f_nw    = (const float*)d_in[9];
  const float* f_ow    = (const float*)d_in[10];
  const float* b_ln_w  = (const float*)d_in[11];
  const float* b_ln_b  = (const float*)d_in[12];
  const float* b_in_w  = (const float*)d_in[13];
  const float* b_cw    = (const float*)d_in[14];
  const float* b_cb    = (const float*)d_in[15];
  const float* b_dtb   = (const float*)d_in[16];
  const float* b_alog  = (const float*)d_in[17];
  const float* b_D     = (const float*)d_in[18];
  const float* b_nw    = (const float*)d_in[19];
  const float* b_ow    = (const float*)d_in[20];

  char* ws = (char*)d_ws;
  size_t off = 0;
  auto carve = [&](size_t bytes) -> char* {
    off = (off + 255) & ~(size_t)255;
    char* p = ws + off;
    off += bytes;
    return p;
  };
  ushortT* XLN   = (ushortT*)carve((size_t)2 * ROWS * DM * 2);
  ushortT* WP1   = (ushortT*)carve((size_t)2 * NP1 * DM * 2);
  ushortT* W2    = (ushortT*)carve((size_t)2 * DM * DI * 2);
  ushortT* ZXB   = (ushortT*)carve((size_t)2 * ROWS * NP1 * 2);
  float*   DTT   = (float*)carve((size_t)2 * ROWS * 128 * 4);
  ushortT* XCB   = (ushortT*)carve((size_t)2 * ROWS * CONVD * 2);
  float*   DTS   = (float*)carve((size_t)2 * ROWS * HH * 4);
  float*   LDA   = (float*)carve((size_t)2 * ROWS * HH * 4);
  ushortT* YB    = (ushortT*)carve((size_t)2 * ROWS * DI * 2);
  ushortT* YIB   = (ushortT*)carve((size_t)2 * ROWS * DI * 2);
  ushortT* YN    = (ushortT*)carve((size_t)2 * ROWS * DI * 2);
  float*   MOUT  = (float*)carve((size_t)2 * ROWS * DM * 4);
  ushortT* SLOCB = (ushortT*)carve((size_t)96 * NCHUNK * 4096 * 2);
  ushortT* SINIB = (ushortT*)carve((size_t)96 * (NCHUNK - 1) * 4096 * 2);
  ushortT* CBG   = (ushortT*)carve((size_t)4 * NCHUNK * 4096 * 2);
  float*   CWG   = (float*)carve((size_t)2 * ROWS * HH * 4);

  // weight conversion (merged)
  cvt_all_kernel<<<2048, 256, 0, stream>>>(f_in_w, b_in_w, f_ow, b_ow, WP1, W2);

  // layernorm (both dirs)
  ln_kernel<<<4096, 256, 0, stream>>>(x, f_ln_w, f_ln_b, b_ln_w, b_ln_b, XLN);

  // in_proj: [2048,768] x [3328,768]^T -> bf16 z/xBC + f32 dt tail
  gemm_bf16<1><<<dim3(NP1 / 128, ROWS / 128, 2), 256, 0, stream>>>(
      XLN, WP1, DTT, ZXB, DM, DM, DM, NP1,
      (long)ROWS * DM, (long)NP1 * DM, (long)ROWS * 128, (long)ROWS * NP1);

  // conv + dt/logdA
  conv_dt_kernel<<<4096, 256, 0, stream>>>(ZXB, DTT, f_cw, f_cb, b_cw, b_cb,
                                           f_dtb, f_alog, b_dtb, b_alog,
                                           XCB, DTS, LDA);

  // chunked scan: pass 1 (SSD/MFMA), pass 2 (prefix), pass 3 (MFMA fixup)
  ssd_chunk_kernel<<<dim3(96, NCHUNK), 256, 0, stream>>>(XCB, DTS, LDA, YB, SLOCB, CWG, CBG);
  chunk_prefix_kernel<<<96, 256, 0, stream>>>(SLOCB, CWG, SINIB);
  fixup_kernel<<<dim3(96, NCHUNK - 1), 256, 0, stream>>>(CBG, SINIB, CWG, YIB);

  // gate + rmsnorm
  gate_norm_kernel<<<4096, 256, 0, stream>>>(YB, YIB, ZXB, XCB, f_D, b_D, f_nw, b_nw, YN);

  // out_proj: [2048,1536] x [768,1536]^T -> [2048,768] f32
  gemm_bf16<0><<<dim3(DM / 128, ROWS / 128, 2), 256, 0, stream>>>(
      YN, W2, MOUT, nullptr, DI, DI, DI, DM,
      (long)ROWS * DI, (long)DM * DI, (long)ROWS * DM, 0);

  // combine
  combine_kernel<<<2048, 256, 0, stream>>>(x, MOUT, MOUT + (size_t)ROWS * DM, (float*)d_out);
}

// Round 5
// 182.044 us; speedup vs baseline: 3.3584x; 1.0622x over previous
//
#include <hip/hip_runtime.h>
#include <cstdint>

#define DM    768
#define DI    1536
#define PP    64
#define HH    24
#define NN    64
#define CONVD 1664
#define DINP  3224
#define NP1   3328   // 3224 padded to 26*128
#define LL    1024
#define ROWS  2048   // BATCH*LL
#define EPSF  1e-5f
#define NCHUNK 16
#define CLEN   64

typedef unsigned short ushortT;
typedef __attribute__((ext_vector_type(8))) __bf16 bf16x8;
typedef __attribute__((ext_vector_type(8))) unsigned short ushort8;
typedef __attribute__((ext_vector_type(4))) float f32x4;

__device__ __forceinline__ int seqmap(int t) { return 1023 - 32 * (t & 31) - (t >> 5); }

__device__ __forceinline__ ushortT f2bf(float f) {
  union { float f; unsigned u; } v; v.f = f;
  unsigned r = v.u + 0x7FFF + ((v.u >> 16) & 1);
  return (ushortT)(r >> 16);
}
__device__ __forceinline__ float bf2f(ushortT b) {
  union { unsigned u; float f; } v; v.u = ((unsigned)b) << 16;
  return v.f;
}

__device__ __forceinline__ void gload_lds16(const void* g, void* l) {
  __builtin_amdgcn_global_load_lds((const __attribute__((address_space(1))) void*)g,
                                   (__attribute__((address_space(3))) void*)l, 16, 0, 0);
}

// swizzled ushort index into a 64x64 bf16 tile (row stride 64)
#define SWZ(r, c) ((r) * 64 + ((c) ^ (((r) & 7) << 3)))
// swizzled ushort index into a [128][32] bf16 tile (row stride 32), per-oct conflict-free
#define SWZG(r, c) ((r) * 32 + ((c) ^ ((((r) >> 1) & 3) << 3)))

// ---------------- merged weight convert (f32 -> bf16, zero-pad tail) ----------------
__global__ __launch_bounds__(256) void cvt_all_kernel(
    const float* __restrict__ fw1, const float* __restrict__ bw1,
    const float* __restrict__ fw2, const float* __restrict__ bw2,
    ushortT* __restrict__ WP1, ushortT* __restrict__ W2) {
  const long NW1 = (long)NP1 * DM, SW1 = (long)DINP * DM, NW2 = (long)DM * DI;
  const long total = 2 * NW1 + 2 * NW2;
  for (long i = (long)blockIdx.x * 256 + threadIdx.x; i < total; i += (long)gridDim.x * 256) {
    if (i < NW1) {
      WP1[i] = (i < SW1) ? f2bf(fw1[i]) : (ushortT)0;
    } else if (i < 2 * NW1) {
      long j = i - NW1;
      WP1[i] = (j < SW1) ? f2bf(bw1[j]) : (ushortT)0;
    } else if (i < 2 * NW1 + NW2) {
      long j = i - 2 * NW1;
      W2[j] = f2bf(fw2[j]);
    } else {
      long j = i - 2 * NW1 - NW2;
      W2[NW2 + j] = f2bf(bw2[j]);
    }
  }
}

// ---------------- LayerNorm (both dirs; dir1 gathers via SEQ) ----------------
__global__ __launch_bounds__(256) void ln_kernel(const float* __restrict__ x,
    const float* __restrict__ wf, const float* __restrict__ bf_,
    const float* __restrict__ wb, const float* __restrict__ bb,
    ushortT* __restrict__ xln) {
  __shared__ float lds[4];
  int bid = blockIdx.x;
  int dir = bid >> 11, row = bid & 2047;
  int b = row >> 10, t = row & 1023;
  int st = dir ? seqmap(t) : t;
  const float* xr = x + (size_t)(b * 1024 + st) * DM;
  const float* w = dir ? wb : wf;
  const float* bia = dir ? bb : bf_;
  int tid = threadIdx.x;
  float v0 = xr[tid], v1 = xr[tid + 256], v2 = xr[tid + 512];
  float s = v0 + v1 + v2;
  #pragma unroll
  for (int o = 32; o; o >>= 1) s += __shfl_xor(s, o, 64);
  if ((tid & 63) == 0) lds[tid >> 6] = s;
  __syncthreads();
  float mean = (lds[0] + lds[1] + lds[2] + lds[3]) * (1.f / 768.f);
  __syncthreads();
  float d0 = v0 - mean, d1 = v1 - mean, d2 = v2 - mean;
  float q = d0 * d0 + d1 * d1 + d2 * d2;
  #pragma unroll
  for (int o = 32; o; o >>= 1) q += __shfl_xor(q, o, 64);
  if ((tid & 63) == 0) lds[tid >> 6] = q;
  __syncthreads();
  float var = (lds[0] + lds[1] + lds[2] + lds[3]) * (1.f / 768.f);
  float rs = rsqrtf(var + EPSF);
  ushortT* orow = xln + (size_t)bid * DM;
  orow[tid]       = f2bf(d0 * rs * w[tid]       + bia[tid]);
  orow[tid + 256] = f2bf(d1 * rs * w[tid + 256] + bia[tid + 256]);
  orow[tid + 512] = f2bf(d2 * rs * w[tid + 512] + bia[tid + 512]);
}

// ---------------- bf16 MFMA GEMM: C[M,N] = A[M,K] * B[N,K]^T ----------------
// Double-buffered LDS, single barrier per K-step, prefetch-before-compute,
// T2 both-sides swizzle, T1 XCD-aware block swizzle.
// MODE 0: bf16 output to Cb. MODE 1: bf16 to Cb for n0<3200, f32 to Cf (dt tail, ld 128).
template<int MODE>
__global__ __launch_bounds__(256) void gemm_bf16(
    const ushortT* __restrict__ Aall, const ushortT* __restrict__ Ball,
    float* __restrict__ Cfall, ushortT* __restrict__ Cball,
    int K, int lda, int ldb, int ldc, long sA, long sB, long sCf, long sCb) {
  __shared__ ushortT sA2[2][128 * 32];
  __shared__ ushortT sB2[2][128 * 32];
  // T1: XCD-aware remap of flat block id (nwg % 8 == 0 for both launches)
  int gx = gridDim.x, gy = gridDim.y;
  int nwg = gx * gy * gridDim.z;
  int lid = blockIdx.x + gx * (blockIdx.y + gy * blockIdx.z);
  int cpx = nwg >> 3;
  int swz = (lid & 7) * cpx + (lid >> 3);
  int bx = swz % gx;
  int rest = swz / gx;
  int by = rest % gy, bz = rest / gy;
  const ushortT* A = Aall + (size_t)bz * sA;
  const ushortT* B = Ball + (size_t)bz * sB;
  int tid = threadIdx.x, lane = tid & 63, w = tid >> 6;
  int wm = w >> 1, wn = w & 1;
  int m0 = by * 128, n0 = bx * 128;
  int rA = lane >> 2;
  int cA = ((lane & 3) * 8) ^ (((lane >> 3) & 3) << 3);   // pre-swizzled source col
  f32x4 acc[4][4] = {};
  const int NT = K >> 5;
  int cur = 0;
  // prologue: stage tile 0
  #pragma unroll
  for (int c = 0; c < 2; ++c) {
    int q = w * 2 + c;
    gload_lds16(A + (size_t)(m0 + q * 16 + rA) * lda + cA, &sA2[0][q * 512]);
    gload_lds16(B + (size_t)(n0 + q * 16 + rA) * ldb + cA, &sB2[0][q * 512]);
  }
  __syncthreads();
  int fr = lane & 15, kk = (lane >> 4) * 8;
  for (int kt = 0; kt < NT; ++kt) {
    if (kt + 1 < NT) {
      int kc = (kt + 1) * 32 + cA;
      #pragma unroll
      for (int c = 0; c < 2; ++c) {
        int q = w * 2 + c;
        gload_lds16(A + (size_t)(m0 + q * 16 + rA) * lda + kc, &sA2[cur ^ 1][q * 512]);
        gload_lds16(B + (size_t)(n0 + q * 16 + rA) * ldb + kc, &sB2[cur ^ 1][q * 512]);
      }
    }
    bf16x8 af[4], bfr[4];
    #pragma unroll
    for (int i = 0; i < 4; ++i)
      af[i] = *(const bf16x8*)&sA2[cur][SWZG(wm * 64 + i * 16 + fr, kk)];
    #pragma unroll
    for (int j = 0; j < 4; ++j)
      bfr[j] = *(const bf16x8*)&sB2[cur][SWZG(wn * 64 + j * 16 + fr, kk)];
    #pragma unroll
    for (int i = 0; i < 4; ++i)
      #pragma unroll
      for (int j = 0; j < 4; ++j)
        acc[i][j] = __builtin_amdgcn_mfma_f32_16x16x32_bf16(af[i], bfr[j], acc[i][j], 0, 0, 0);
    __syncthreads();
    cur ^= 1;
  }
  int cr = (lane >> 4) * 4, cc = lane & 15;
  if (MODE == 1 && n0 >= 3200) {
    float* Cf = Cfall + (size_t)bz * sCf;
    #pragma unroll
    for (int i = 0; i < 4; ++i)
      #pragma unroll
      for (int j = 0; j < 4; ++j) {
        float* Cp = Cf + (size_t)(m0 + wm * 64 + i * 16 + cr) * 128 + (wn * 64 + j * 16 + cc);
        #pragma unroll
        for (int r = 0; r < 4; ++r) Cp[(size_t)r * 128] = acc[i][j][r];
      }
  } else {
    ushortT* Cb = Cball + (size_t)bz * sCb;
    #pragma unroll
    for (int i = 0; i < 4; ++i)
      #pragma unroll
      for (int j = 0; j < 4; ++j) {
        ushortT* Cp = Cb + (size_t)(m0 + wm * 64 + i * 16 + cr) * ldc + (n0 + wn * 64 + j * 16 + cc);
        #pragma unroll
        for (int r = 0; r < 4; ++r) Cp[(size_t)r * ldc] = f2bf(acc[i][j][r]);
      }
  }
}

// ---------------- conv(K=4 causal, depthwise) + silu + dt/logdA precompute ----------------
__global__ __launch_bounds__(256) void conv_dt_kernel(const ushortT* __restrict__ zxb,
    const float* __restrict__ dtt,
    const float* __restrict__ cwf, const float* __restrict__ cbf,
    const float* __restrict__ cwb, const float* __restrict__ cbb,
    const float* __restrict__ dtbf, const float* __restrict__ alogf,
    const float* __restrict__ dtbb, const float* __restrict__ alogb,
    ushortT* __restrict__ xcb, float* __restrict__ dts, float* __restrict__ lda_) {
  int bid = blockIdx.x;
  int dir = bid >> 11, row = bid & 2047;
  int t = row & 1023;
  const float* cw   = dir ? cwb : cwf;
  const float* cb   = dir ? cbb : cbf;
  const float* dtb  = dir ? dtbb : dtbf;
  const float* alog = dir ? alogb : alogf;
  const ushortT* zrow = zxb + (size_t)bid * NP1;
  int tid = threadIdx.x;
  if (tid < HH) {
    float raw = dtt[(size_t)bid * 128 + tid] + dtb[tid];
    float dtv = raw > 20.f ? raw : log1pf(expf(raw));
    dts[(size_t)bid * HH + tid] = dtv;
    lda_[(size_t)bid * HH + tid] = -expf(alog[tid]) * dtv;   // log dA (negative)
  }
  ushortT* xrow = xcb + (size_t)bid * CONVD;
  for (int c = tid; c < CONVD; c += 256) {
    float acc = cb[c];
    #pragma unroll
    for (int k = 0; k < 4; ++k) {
      int tt = t - 3 + k;
      if (tt >= 0) acc += bf2f(zrow[(long)(k - 3) * NP1 + 1536 + c]) * cw[c * 4 + k];
    }
    xrow[c] = f2bf(acc / (1.f + expf(-acc)));
  }
}

// ---------------- pass 1 (SSD form): block per (gh, chunk) ----------------
__global__ __launch_bounds__(256) void ssd_chunk_kernel(const ushortT* __restrict__ xcb,
    const float* __restrict__ dts, const float* __restrict__ lda_,
    ushortT* __restrict__ yb, ushortT* __restrict__ slocb, float* __restrict__ cwg,
    ushortT* __restrict__ cbg) {
  __shared__ ushortT sCb[4096];   // [t][n]
  __shared__ ushortT sBb[4096];   // [s][n]
  __shared__ ushortT sBT[4096];   // [n][t]  (weighted)
  __shared__ ushortT sXT[4096];   // [p][t]
  __shared__ ushortT sMb[4096];   // [t][s]
  __shared__ float clog[64];
  __shared__ float dt64[64];
  __shared__ float wv64[64];
  int gh = blockIdx.x;                 // dir*48 + b*24 + h
  int c  = blockIdx.y;                 // chunk
  int dir = gh / 48;
  int rem = gh % 48;
  int b = rem / 24, h = rem % 24;
  int tid = threadIdx.x, lane = tid & 63;
  int w = tid >> 6;
  size_t rowbase = ((size_t)dir * 2 + b) * 1024;
  size_t trow = rowbase + (size_t)c * CLEN;

  // ---- phase 1: stage C, B (ushort8), X^T (scalar transpose) ----
  #pragma unroll
  for (int it2 = 0; it2 < 2; ++it2) {
    int idx2 = it2 * 256 + tid;
    int r = idx2 >> 3, c8 = (idx2 & 7) << 3;
    const ushortT* xrow = xcb + (trow + r) * CONVD;
    *(ushort8*)&sCb[SWZ(r, c8)] = *(const ushort8*)&xrow[1600 + c8];
    *(ushort8*)&sBb[SWZ(r, c8)] = *(const ushort8*)&xrow[1536 + c8];
  }
  #pragma unroll
  for (int it = 0; it < 16; ++it) {
    int idx = it * 256 + tid;
    int r = idx >> 6, cc = idx & 63;
    sXT[SWZ(cc, r)] = xcb[(trow + r) * CONVD + h * 64 + cc];
  }
  if (tid < 64) {
    float ld = lda_[(trow + tid) * HH + h];
    float dtv = dts[(trow + tid) * HH + h];
    float v = ld;
    #pragma unroll
    for (int o = 1; o < 64; o <<= 1) {
      float u = __shfl_up(v, o, 64);
      if (tid >= o) v += u;
    }
    float tot = __shfl(v, 63, 64);
    clog[tid] = v;
    dt64[tid] = dtv;
    wv64[tid] = dtv * __expf(tot - v);
    cwg[(trow + tid) * HH + h] = __expf(v);
  }
  __syncthreads();

  // dump C tile once per (dir,b,chunk) for the fixup pass
  if (h == 0) {
    ushortT* dst = cbg + ((size_t)((dir * 2 + b) * NCHUNK + c)) * 4096;
    for (int idx = tid; idx < 4096; idx += 256) dst[idx] = sCb[idx];
  }

  int fr = lane & 15, kq = lane >> 4;

  // ---- phase 2: weighted B^T; G = C.B^T; decay -> M(bf16) ----
  #pragma unroll
  for (int it = 0; it < 16; ++it) {
    int idx = it * 256 + tid;
    int s = idx >> 6, n = idx & 63;
    float bv = bf2f(sBb[SWZ(s, n)]) * wv64[s];
    sBT[SWZ(n, s)] = f2bf(bv);
  }
  f32x4 accG[4] = {};
  #pragma unroll
  for (int kt = 0; kt < 2; ++kt) {
    int kk = kt * 32 + kq * 8;
    bf16x8 af = *(const bf16x8*)&sCb[SWZ(w * 16 + fr, kk)];
    #pragma unroll
    for (int j = 0; j < 4; ++j) {
      bf16x8 bf_ = *(const bf16x8*)&sBb[SWZ(j * 16 + fr, kk)];
      accG[j] = __builtin_amdgcn_mfma_f32_16x16x32_bf16(af, bf_, accG[j], 0, 0, 0);
    }
  }
  #pragma unroll
  for (int j = 0; j < 4; ++j) {
    int s = j * 16 + fr;
    float cls = clog[s], dtv = dt64[s];
    #pragma unroll
    for (int r = 0; r < 4; ++r) {
      int t = w * 16 + kq * 4 + r;
      float dec = (s <= t) ? __expf(clog[t] - cls) * dtv : 0.f;
      sMb[SWZ(t, s)] = f2bf(accG[j][r] * dec);
    }
  }
  __syncthreads();

  // ---- phase 3: Y = M.X ; S = wB^T.X (shared X fragments) ----
  f32x4 accY[4] = {}, accS[4] = {};
  #pragma unroll
  for (int kt = 0; kt < 2; ++kt) {
    int kk = kt * 32 + kq * 8;
    bf16x8 aM = *(const bf16x8*)&sMb[SWZ(w * 16 + fr, kk)];
    bf16x8 aB = *(const bf16x8*)&sBT[SWZ(w * 16 + fr, kk)];
    #pragma unroll
    for (int j = 0; j < 4; ++j) {
      bf16x8 bx = *(const bf16x8*)&sXT[SWZ(j * 16 + fr, kk)];
      accY[j] = __builtin_amdgcn_mfma_f32_16x16x32_bf16(aM, bx, accY[j], 0, 0, 0);
      accS[j] = __builtin_amdgcn_mfma_f32_16x16x32_bf16(aB, bx, accS[j], 0, 0, 0);
    }
  }
  ushortT* spb = slocb + ((size_t)gh * NCHUNK + c) * 4096;
  #pragma unroll
  for (int j = 0; j < 4; ++j) {
    #pragma unroll
    for (int r = 0; r < 4; ++r) {
      int t = w * 16 + kq * 4 + r;        // row (t for Y, n for S)
      int p = j * 16 + fr;                // col
      yb[(trow + t) * DI + h * 64 + p] = f2bf(accY[j][r]);
      spb[t * 64 + p] = f2bf(accS[j][r]);
    }
  }
}

// ---------------- pass 2: serial prefix over chunk states (96 blocks) ----------------
__global__ __launch_bounds__(256) void chunk_prefix_kernel(
    const ushortT* __restrict__ slocb, const float* __restrict__ cwg,
    ushortT* __restrict__ sinitb) {
  __shared__ float ldsT[64 * 65];
  int gh = blockIdx.x;
  int dir = gh / 48;
  int rem = gh % 48;
  int b = rem / 24, h = rem % 24;
  int tid = threadIdx.x;
  size_t rowbase = ((size_t)dir * 2 + b) * 1024;
  float R[16];
  #pragma unroll
  for (int j = 0; j < 16; ++j) R[j] = 0.f;
  for (int c = 1; c < NCHUNK; ++c) {
    float W = cwg[(rowbase + (size_t)c * CLEN - 1) * HH + h];
    const ushortT* slot = slocb + ((size_t)gh * NCHUNK + (c - 1)) * 4096;
    #pragma unroll
    for (int j = 0; j < 16; ++j) {
      int idx = j * 256 + tid, n = idx >> 6, p = idx & 63;
      R[j] = __builtin_fmaf(R[j], W, bf2f(slot[idx]));
      ldsT[n * 65 + p] = R[j];
    }
    __syncthreads();
    ushortT* outp = sinitb + ((size_t)gh * (NCHUNK - 1) + (c - 1)) * 4096;
    #pragma unroll
    for (int j = 0; j < 16; ++j) {
      int idx = j * 256 + tid, p = idx >> 6, n = idx & 63;
      outp[SWZ(p, n)] = f2bf(ldsT[n * 65 + p]);
    }
    __syncthreads();
  }
}

// ---------------- pass 3 (MFMA): YI[t,p] = cw[t] * (C_t . S_init) ----------------
__global__ __launch_bounds__(256) void fixup_kernel(
    const ushortT* __restrict__ cbg, const ushortT* __restrict__ sinitb,
    const float* __restrict__ cwg, ushortT* __restrict__ yib) {
  __shared__ ushortT sCb[4096];
  __shared__ ushortT sST[4096];
  int gh = blockIdx.x;
  int c = blockIdx.y + 1;      // 1..15
  int dir = gh / 48;
  int rem = gh % 48;
  int b = rem / 24, h = rem % 24;
  int tid = threadIdx.x, lane = tid & 63, w = tid >> 6;
  size_t rowbase = ((size_t)dir * 2 + b) * 1024;
  size_t trow = rowbase + (size_t)c * CLEN;
  const ushortT* cbSrc = cbg + ((size_t)((dir * 2 + b) * NCHUNK + c)) * 4096;
  const ushortT* stSrc = sinitb + ((size_t)gh * (NCHUNK - 1) + (c - 1)) * 4096;
  #pragma unroll
  for (int ph = 0; ph < 2; ++ph) {
    int base = ph * 2048 + w * 512;
    gload_lds16(cbSrc + base + lane * 8, &sCb[base]);
    gload_lds16(stSrc + base + lane * 8, &sST[base]);
  }
  __syncthreads();
  int fr = lane & 15, kq = lane >> 4;
  f32x4 accY[4] = {};
  #pragma unroll
  for (int kt = 0; kt < 2; ++kt) {
    int kk = kt * 32 + kq * 8;
    bf16x8 aC = *(const bf16x8*)&sCb[SWZ(w * 16 + fr, kk)];
    #pragma unroll
    for (int j = 0; j < 4; ++j) {
      bf16x8 bS = *(const bf16x8*)&sST[SWZ(j * 16 + fr, kk)];
      accY[j] = __builtin_amdgcn_mfma_f32_16x16x32_bf16(aC, bS, accY[j], 0, 0, 0);
    }
  }
  float cwv[4];
  #pragma unroll
  for (int r = 0; r < 4; ++r)
    cwv[r] = cwg[(trow + w * 16 + kq * 4 + r) * HH + h];
  #pragma unroll
  for (int j = 0; j < 4; ++j)
    #pragma unroll
    for (int r = 0; r < 4; ++r) {
      int t = w * 16 + kq * 4 + r, p = j * 16 + fr;
      yib[(trow + t) * DI + h * 64 + p] = f2bf(accY[j][r] * cwv[r]);
    }
}

// ---------------- +D*xs, gate silu(z), RMSNorm, -> bf16 ----------------
__global__ __launch_bounds__(256) void gate_norm_kernel(
    const ushortT* __restrict__ yb, const ushortT* __restrict__ yib,
    const ushortT* __restrict__ zxb, const ushortT* __restrict__ xcb,
    const float* __restrict__ Df, const float* __restrict__ Db,
    const float* __restrict__ nwf, const float* __restrict__ nwb,
    ushortT* __restrict__ yn) {
  __shared__ float lds[4];
  int bid = blockIdx.x;            // 0..4095 (dir*2048 + b*1024 + t)
  int dir = bid >> 11;
  int t = bid & 1023;
  const float* Dp = dir ? Db : Df;
  const float* nw = dir ? nwb : nwf;
  int tid = threadIdx.x;
  bool act = tid < 192;
  int c0 = tid * 8;
  float v[8];
  float ss = 0.f;
  if (act) {
    ushort8 yv8 = *(const ushort8*)&yb[(size_t)bid * DI + c0];
    ushort8 zv8 = *(const ushort8*)&zxb[(size_t)bid * NP1 + c0];
    ushort8 xv8 = *(const ushort8*)&xcb[(size_t)bid * CONVD + c0];
    ushort8 yi8 = {};
    bool hasI = (t >= CLEN);
    if (hasI) yi8 = *(const ushort8*)&yib[(size_t)bid * DI + c0];
    float Dv = Dp[c0 >> 6];
    #pragma unroll
    for (int e = 0; e < 8; ++e) {
      float yv = bf2f(yv8[e]) + (hasI ? bf2f(yi8[e]) : 0.f) + Dv * bf2f(xv8[e]);
      float zv = bf2f(zv8[e]);
      yv *= zv / (1.f + expf(-zv));
      v[e] = yv;
      ss += yv * yv;
    }
  }
  #pragma unroll
  for (int o = 32; o; o >>= 1) ss += __shfl_xor(ss, o, 64);
  if ((tid & 63) == 0) lds[tid >> 6] = ss;
  __syncthreads();
  float ms = (lds[0] + lds[1] + lds[2] + lds[3]) * (1.f / 1536.f);
  float sc = rsqrtf(ms + EPSF);
  if (act) {
    ushort8 o8;
    #pragma unroll
    for (int e = 0; e < 8; ++e) o8[e] = f2bf(v[e] * sc * nw[c0 + e]);
    *(ushort8*)&yn[(size_t)bid * DI + c0] = o8;
  }
}

// ---------------- out[t] = 2x[t] + mf[t] + mb[SEQ[t]] (mf/mb bf16) ----------------
__global__ __launch_bounds__(128) void combine_kernel(const float* __restrict__ x,
    const ushortT* __restrict__ mf, const ushortT* __restrict__ mb,
    float* __restrict__ out) {
  int bid = blockIdx.x;   // b*1024 + t
  int b = bid >> 10, t = bid & 1023;
  int st = seqmap(t);
  int tid = threadIdx.x;
  if (tid >= 96) return;
  int c0 = tid * 8;
  ushort8 fv = *(const ushort8*)&mf[(size_t)bid * DM + c0];
  ushort8 bv = *(const ushort8*)&mb[(size_t)(b * 1024 + st) * DM + c0];
  const float4 x0 = *(const float4*)&x[(size_t)bid * DM + c0];
  const float4 x1 = *(const float4*)&x[(size_t)bid * DM + c0 + 4];
  float4 o0, o1;
  o0.x = 2.f * x0.x + bf2f(fv[0]) + bf2f(bv[0]);
  o0.y = 2.f * x0.y + bf2f(fv[1]) + bf2f(bv[1]);
  o0.z = 2.f * x0.z + bf2f(fv[2]) + bf2f(bv[2]);
  o0.w = 2.f * x0.w + bf2f(fv[3]) + bf2f(bv[3]);
  o1.x = 2.f * x1.x + bf2f(fv[4]) + bf2f(bv[4]);
  o1.y = 2.f * x1.y + bf2f(fv[5]) + bf2f(bv[5]);
  o1.z = 2.f * x1.z + bf2f(fv[6]) + bf2f(bv[6]);
  o1.w = 2.f * x1.w + bf2f(fv[7]) + bf2f(bv[7]);
  *(float4*)&out[(size_t)bid * DM + c0] = o0;
  *(float4*)&out[(size_t)bid * DM + c0 + 4] = o1;
}

extern "C" void kernel_launch(void* const* d_in, const int* in_sizes, int n_in,
                              void* d_out, int out_size, void* d_ws, size_t ws_size,
                              hipStream_t stream) {
  const float* x       = (const float*)d_in[0];
  const float* f_ln_w  = (const float*)d_in[1];
  const float* f_ln_b  = (const float*)d_in[2];
  const float* f_in_w  = (const float*)d_in[3];
  const float* f_cw    = (const float*)d_in[4];
  const float* f_cb    = (const float*)d_in[5];
  const float* f_dtb   = (const float*)d_in[6];
  const float* f_alog  = (const float*)d_in[7];
  const float* f_D     = (const float*)d_in[8];
  const float* f_nw    = (const float*)d_in[9];
  const float* f_ow    = (const float*)d_in[10];
  const float* b_ln_w  = (const float*)d_in[11];
  const float* b_ln_b  = (const float*)d_in[12];
  const float* b_in_w  = (const float*)d_in[13];
  const float* b_cw    = (const float*)d_in[14];
  const float* b_cb    = (const float*)d_in[15];
  const float* b_dtb   = (const float*)d_in[16];
  const float* b_alog  = (const float*)d_in[17];
  const float* b_D     = (const float*)d_in[18];
  const float* b_nw    = (const float*)d_in[19];
  const float* b_ow    = (const float*)d_in[20];

  char* ws = (char*)d_ws;
  size_t off = 0;
  auto carve = [&](size_t bytes) -> char* {
    off = (off + 255) & ~(size_t)255;
    char* p = ws + off;
    off += bytes;
    return p;
  };
  ushortT* XLN   = (ushortT*)carve((size_t)2 * ROWS * DM * 2);
  ushortT* WP1   = (ushortT*)carve((size_t)2 * NP1 * DM * 2);
  ushortT* W2    = (ushortT*)carve((size_t)2 * DM * DI * 2);
  ushortT* ZXB   = (ushortT*)carve((size_t)2 * ROWS * NP1 * 2);
  float*   DTT   = (float*)carve((size_t)2 * ROWS * 128 * 4);
  ushortT* XCB   = (ushortT*)carve((size_t)2 * ROWS * CONVD * 2);
  float*   DTS   = (float*)carve((size_t)2 * ROWS * HH * 4);
  float*   LDA   = (float*)carve((size_t)2 * ROWS * HH * 4);
  ushortT* YB    = (ushortT*)carve((size_t)2 * ROWS * DI * 2);
  ushortT* YIB   = (ushortT*)carve((size_t)2 * ROWS * DI * 2);
  ushortT* YN    = (ushortT*)carve((size_t)2 * ROWS * DI * 2);
  ushortT* MOUTB = (ushortT*)carve((size_t)2 * ROWS * DM * 2);
  ushortT* SLOCB = (ushortT*)carve((size_t)96 * NCHUNK * 4096 * 2);
  ushortT* SINIB = (ushortT*)carve((size_t)96 * (NCHUNK - 1) * 4096 * 2);
  ushortT* CBG   = (ushortT*)carve((size_t)4 * NCHUNK * 4096 * 2);
  float*   CWG   = (float*)carve((size_t)2 * ROWS * HH * 4);

  // weight conversion (merged)
  cvt_all_kernel<<<2048, 256, 0, stream>>>(f_in_w, b_in_w, f_ow, b_ow, WP1, W2);

  // layernorm (both dirs)
  ln_kernel<<<4096, 256, 0, stream>>>(x, f_ln_w, f_ln_b, b_ln_w, b_ln_b, XLN);

  // in_proj: [2048,768] x [3328,768]^T -> bf16 z/xBC + f32 dt tail
  gemm_bf16<1><<<dim3(NP1 / 128, ROWS / 128, 2), 256, 0, stream>>>(
      XLN, WP1, DTT, ZXB, DM, DM, DM, NP1,
      (long)ROWS * DM, (long)NP1 * DM, (long)ROWS * 128, (long)ROWS * NP1);

  // conv + dt/logdA
  conv_dt_kernel<<<4096, 256, 0, stream>>>(ZXB, DTT, f_cw, f_cb, b_cw, b_cb,
                                           f_dtb, f_alog, b_dtb, b_alog,
                                           XCB, DTS, LDA);

  // chunked scan: pass 1 (SSD/MFMA), pass 2 (prefix), pass 3 (MFMA fixup)
  ssd_chunk_kernel<<<dim3(96, NCHUNK), 256, 0, stream>>>(XCB, DTS, LDA, YB, SLOCB, CWG, CBG);
  chunk_prefix_kernel<<<96, 256, 0, stream>>>(SLOCB, CWG, SINIB);
  fixup_kernel<<<dim3(96, NCHUNK - 1), 256, 0, stream>>>(CBG, SINIB, CWG, YIB);

  // gate + rmsnorm
  gate_norm_kernel<<<4096, 256, 0, stream>>>(YB, YIB, ZXB, XCB, f_D, b_D, f_nw, b_nw, YN);

  // out_proj: [2048,1536] x [768,1536]^T -> [2048,768] bf16
  gemm_bf16<0><<<dim3(DM / 128, ROWS / 128, 2), 256, 0, stream>>>(
      YN, W2, nullptr, MOUTB, DI, DI, DI, DM,
      (long)ROWS * DI, (long)DM * DI, 0, (long)ROWS * DM);

  // combine
  combine_kernel<<<2048, 128, 0, stream>>>(x, MOUTB, MOUTB + (size_t)ROWS * DM, (float*)d_out);
}

// Round 6
// 164.631 us; speedup vs baseline: 3.7136x; 1.1058x over previous
//
#include <hip/hip_runtime.h>
#include <cstdint>

#define DM    768
#define DI    1536
#define PP    64
#define HH    24
#define NN    64
#define CONVD 1664
#define DINP  3224
#define NP1   3328   // 3224 padded to 26*128
#define LL    1024
#define ROWS  2048   // BATCH*LL
#define EPSF  1e-5f
#define NCHUNK 16
#define CLEN   64

typedef unsigned short ushortT;
typedef __attribute__((ext_vector_type(8))) __bf16 bf16x8;
typedef __attribute__((ext_vector_type(8))) unsigned short ushort8;
typedef __attribute__((ext_vector_type(4))) float f32x4;

__device__ __forceinline__ int seqmap(int t) { return 1023 - 32 * (t & 31) - (t >> 5); }

__device__ __forceinline__ ushortT f2bf(float f) {
  union { float f; unsigned u; } v; v.f = f;
  unsigned r = v.u + 0x7FFF + ((v.u >> 16) & 1);
  return (ushortT)(r >> 16);
}
__device__ __forceinline__ float bf2f(ushortT b) {
  union { unsigned u; float f; } v; v.u = ((unsigned)b) << 16;
  return v.f;
}

__device__ __forceinline__ void gload_lds16(const void* g, void* l) {
  __builtin_amdgcn_global_load_lds((const __attribute__((address_space(1))) void*)g,
                                   (__attribute__((address_space(3))) void*)l, 16, 0, 0);
}

// swizzled ushort index into a 64x64 bf16 tile (row stride 64)
#define SWZ(r, c) ((r) * 64 + ((c) ^ (((r) & 7) << 3)))
// swizzled ushort index into a [128][64] bf16 tile (row stride 64)
#define SWZ64(r, c) ((r) * 64 + ((c) ^ (((r) & 7) << 3)))

// ---------------- merged weight convert (f32 -> bf16, zero-pad tail), vectorized ----------------
__global__ __launch_bounds__(256) void cvt_all_kernel(
    const float* __restrict__ fw1, const float* __restrict__ bw1,
    const float* __restrict__ fw2, const float* __restrict__ bw2,
    ushortT* __restrict__ WP1, ushortT* __restrict__ W2) {
  const long NW1 = (long)NP1 * DM, SW1 = (long)DINP * DM, NW2 = (long)DM * DI;
  const long tot8 = (2 * NW1 + 2 * NW2) >> 3;
  for (long i8 = (long)blockIdx.x * 256 + threadIdx.x; i8 < tot8; i8 += (long)gridDim.x * 256) {
    long i = i8 << 3;
    const float* src = nullptr;
    ushortT* dst;
    if (i < NW1) {
      if (i < SW1) src = fw1 + i;
      dst = WP1 + i;
    } else if (i < 2 * NW1) {
      long j = i - NW1;
      if (j < SW1) src = bw1 + j;
      dst = WP1 + i;
    } else if (i < 2 * NW1 + NW2) {
      long j = i - 2 * NW1;
      src = fw2 + j;
      dst = W2 + j;
    } else {
      long j = i - 2 * NW1 - NW2;
      src = bw2 + j;
      dst = W2 + NW2 + j;
    }
    ushort8 o = {};
    if (src) {
      float4 a = *(const float4*)src;
      float4 b2 = *(const float4*)(src + 4);
      o[0] = f2bf(a.x);  o[1] = f2bf(a.y);  o[2] = f2bf(a.z);  o[3] = f2bf(a.w);
      o[4] = f2bf(b2.x); o[5] = f2bf(b2.y); o[6] = f2bf(b2.z); o[7] = f2bf(b2.w);
    }
    *(ushort8*)dst = o;
  }
}

// ---------------- LayerNorm (both dirs; dir1 gathers via SEQ) ----------------
__global__ __launch_bounds__(256) void ln_kernel(const float* __restrict__ x,
    const float* __restrict__ wf, const float* __restrict__ bf_,
    const float* __restrict__ wb, const float* __restrict__ bb,
    ushortT* __restrict__ xln) {
  __shared__ float lds[4];
  int bid = blockIdx.x;
  int dir = bid >> 11, row = bid & 2047;
  int b = row >> 10, t = row & 1023;
  int st = dir ? seqmap(t) : t;
  const float* xr = x + (size_t)(b * 1024 + st) * DM;
  const float* w = dir ? wb : wf;
  const float* bia = dir ? bb : bf_;
  int tid = threadIdx.x;
  float v0 = xr[tid], v1 = xr[tid + 256], v2 = xr[tid + 512];
  float s = v0 + v1 + v2;
  #pragma unroll
  for (int o = 32; o; o >>= 1) s += __shfl_xor(s, o, 64);
  if ((tid & 63) == 0) lds[tid >> 6] = s;
  __syncthreads();
  float mean = (lds[0] + lds[1] + lds[2] + lds[3]) * (1.f / 768.f);
  __syncthreads();
  float d0 = v0 - mean, d1 = v1 - mean, d2 = v2 - mean;
  float q = d0 * d0 + d1 * d1 + d2 * d2;
  #pragma unroll
  for (int o = 32; o; o >>= 1) q += __shfl_xor(q, o, 64);
  if ((tid & 63) == 0) lds[tid >> 6] = q;
  __syncthreads();
  float var = (lds[0] + lds[1] + lds[2] + lds[3]) * (1.f / 768.f);
  float rs = rsqrtf(var + EPSF);
  ushortT* orow = xln + (size_t)bid * DM;
  orow[tid]       = f2bf(d0 * rs * w[tid]       + bia[tid]);
  orow[tid + 256] = f2bf(d1 * rs * w[tid + 256] + bia[tid + 256]);
  orow[tid + 512] = f2bf(d2 * rs * w[tid + 512] + bia[tid + 512]);
}

// ---------------- bf16 MFMA GEMM: C[M,N] = A[M,K] * B[N,K]^T ----------------
// BK=64, double-buffered LDS, counted vmcnt + raw barriers (T3+T4 minimal),
// T2 both-sides swizzle, T1 XCD-aware block swizzle.
// MODE 0: bf16 output to Cb. MODE 1: bf16 to Cb for n0<3200, f32 to Cf (dt tail, ld 128).
template<int MODE>
__global__ __launch_bounds__(256) void gemm_bf16(
    const ushortT* __restrict__ Aall, const ushortT* __restrict__ Ball,
    float* __restrict__ Cfall, ushortT* __restrict__ Cball,
    int K, int lda, int ldb, int ldc, long sA, long sB, long sCf, long sCb) {
  __shared__ ushortT sA2[2][128 * 64];
  __shared__ ushortT sB2[2][128 * 64];
  // T1: XCD-aware remap of flat block id (nwg % 8 == 0 for both launches)
  int gx = gridDim.x, gy = gridDim.y;
  int nwg = gx * gy * gridDim.z;
  int lid = blockIdx.x + gx * (blockIdx.y + gy * blockIdx.z);
  int cpx = nwg >> 3;
  int swz = (lid & 7) * cpx + (lid >> 3);
  int bx = swz % gx;
  int rest = swz / gx;
  int by = rest % gy, bz = rest / gy;
  const ushortT* A = Aall + (size_t)bz * sA;
  const ushortT* B = Ball + (size_t)bz * sB;
  int tid = threadIdx.x, lane = tid & 63, w = tid >> 6;
  int wm = w >> 1, wn = w & 1;
  int m0 = by * 128, n0 = bx * 128;
  int rA8 = lane >> 3;
  int cSw = ((lane & 7) << 3) ^ (((lane >> 3) & 7) << 3);   // pre-swizzled source col
  f32x4 acc[4][4] = {};
  const int NT = K >> 6;
  int fr = lane & 15, kq = lane >> 4;

  auto STAGE = [&](int bf, int kt) {
    int kc = kt * 64 + cSw;
    #pragma unroll
    for (int c2 = 0; c2 < 4; ++c2) {
      int q = w * 4 + c2;
      gload_lds16(A + (size_t)(m0 + q * 8 + rA8) * lda + kc, &sA2[bf][q * 512]);
    }
    #pragma unroll
    for (int c2 = 0; c2 < 4; ++c2) {
      int q = w * 4 + c2;
      gload_lds16(B + (size_t)(n0 + q * 8 + rA8) * ldb + kc, &sB2[bf][q * 512]);
    }
  };

  STAGE(0, 0);
  int cur = 0;
  for (int kt = 0; kt < NT; ++kt) {
    if (kt + 1 < NT) {
      STAGE(cur ^ 1, kt + 1);
      asm volatile("s_waitcnt vmcnt(8)" ::: "memory");   // tile kt's 8 loads done
    } else {
      asm volatile("s_waitcnt vmcnt(0)" ::: "memory");
    }
    __builtin_amdgcn_s_barrier();                         // all waves' tile-kt loads done
    __builtin_amdgcn_sched_barrier(0);
    #pragma unroll
    for (int ks = 0; ks < 2; ++ks) {
      int kb = ks * 32 + kq * 8;
      bf16x8 af[4], bfr[4];
      #pragma unroll
      for (int i = 0; i < 4; ++i)
        af[i] = *(const bf16x8*)&sA2[cur][SWZ64(wm * 64 + i * 16 + fr, kb)];
      #pragma unroll
      for (int j = 0; j < 4; ++j)
        bfr[j] = *(const bf16x8*)&sB2[cur][SWZ64(wn * 64 + j * 16 + fr, kb)];
      #pragma unroll
      for (int i = 0; i < 4; ++i)
        #pragma unroll
        for (int j = 0; j < 4; ++j)
          acc[i][j] = __builtin_amdgcn_mfma_f32_16x16x32_bf16(af[i], bfr[j], acc[i][j], 0, 0, 0);
    }
    asm volatile("s_waitcnt lgkmcnt(0)" ::: "memory");    // my LDS reads consumed
    __builtin_amdgcn_sched_barrier(0);
    __builtin_amdgcn_s_barrier();                         // safe to overwrite buf next iter
    cur ^= 1;
  }
  int cr = (lane >> 4) * 4, cc = lane & 15;
  if (MODE == 1 && n0 >= 3200) {
    float* Cf = Cfall + (size_t)bz * sCf;
    #pragma unroll
    for (int i = 0; i < 4; ++i)
      #pragma unroll
      for (int j = 0; j < 4; ++j) {
        float* Cp = Cf + (size_t)(m0 + wm * 64 + i * 16 + cr) * 128 + (wn * 64 + j * 16 + cc);
        #pragma unroll
        for (int r = 0; r < 4; ++r) Cp[(size_t)r * 128] = acc[i][j][r];
      }
  } else {
    ushortT* Cb = Cball + (size_t)bz * sCb;
    #pragma unroll
    for (int i = 0; i < 4; ++i)
      #pragma unroll
      for (int j = 0; j < 4; ++j) {
        ushortT* Cp = Cb + (size_t)(m0 + wm * 64 + i * 16 + cr) * ldc + (n0 + wn * 64 + j * 16 + cc);
        #pragma unroll
        for (int r = 0; r < 4; ++r) Cp[(size_t)r * ldc] = f2bf(acc[i][j][r]);
      }
  }
}

// ---------------- conv(K=4 causal, depthwise) + silu + dt/logdA precompute ----------------
__global__ __launch_bounds__(256) void conv_dt_kernel(const ushortT* __restrict__ zxb,
    const float* __restrict__ dtt,
    const float* __restrict__ cwf, const float* __restrict__ cbf,
    const float* __restrict__ cwb, const float* __restrict__ cbb,
    const float* __restrict__ dtbf, const float* __restrict__ alogf,
    const float* __restrict__ dtbb, const float* __restrict__ alogb,
    ushortT* __restrict__ xcb, float* __restrict__ dts, float* __restrict__ lda_) {
  int bid = blockIdx.x;
  int dir = bid >> 11, row = bid & 2047;
  int t = row & 1023;
  const float* cw   = dir ? cwb : cwf;
  const float* cb   = dir ? cbb : cbf;
  const float* dtb  = dir ? dtbb : dtbf;
  const float* alog = dir ? alogb : alogf;
  const ushortT* zrow = zxb + (size_t)bid * NP1;
  int tid = threadIdx.x;
  if (tid < HH) {
    float raw = dtt[(size_t)bid * 128 + tid] + dtb[tid];
    float dtv = raw > 20.f ? raw : log1pf(expf(raw));
    dts[(size_t)bid * HH + tid] = dtv;
    lda_[(size_t)bid * HH + tid] = -expf(alog[tid]) * dtv;   // log dA (negative)
  }
  ushortT* xrow = xcb + (size_t)bid * CONVD;
  for (int c = tid; c < CONVD; c += 256) {
    float acc = cb[c];
    #pragma unroll
    for (int k = 0; k < 4; ++k) {
      int tt = t - 3 + k;
      if (tt >= 0) acc += bf2f(zrow[(long)(k - 3) * NP1 + 1536 + c]) * cw[c * 4 + k];
    }
    xrow[c] = f2bf(acc / (1.f + expf(-acc)));
  }
}

// ---------------- pass 1 (SSD form): block per (gh, chunk) ----------------
__global__ __launch_bounds__(256) void ssd_chunk_kernel(const ushortT* __restrict__ xcb,
    const float* __restrict__ dts, const float* __restrict__ lda_,
    ushortT* __restrict__ yb, ushortT* __restrict__ slocb, float* __restrict__ cwg,
    ushortT* __restrict__ cbg) {
  __shared__ ushortT sCb[4096];   // [t][n]
  __shared__ ushortT sBb[4096];   // [s][n]
  __shared__ ushortT sBT[4096];   // [n][t]  (weighted)
  __shared__ ushortT sXT[4096];   // [p][t]
  __shared__ ushortT sMb[4096];   // [t][s]
  __shared__ float clog[64];
  __shared__ float dt64[64];
  __shared__ float wv64[64];
  int gh = blockIdx.x;                 // dir*48 + b*24 + h
  int c  = blockIdx.y;                 // chunk
  int dir = gh / 48;
  int rem = gh % 48;
  int b = rem / 24, h = rem % 24;
  int tid = threadIdx.x, lane = tid & 63;
  int w = tid >> 6;
  size_t rowbase = ((size_t)dir * 2 + b) * 1024;
  size_t trow = rowbase + (size_t)c * CLEN;

  // ---- phase 1: stage C, B (ushort8), X^T (scalar transpose) ----
  #pragma unroll
  for (int it2 = 0; it2 < 2; ++it2) {
    int idx2 = it2 * 256 + tid;
    int r = idx2 >> 3, c8 = (idx2 & 7) << 3;
    const ushortT* xrow = xcb + (trow + r) * CONVD;
    *(ushort8*)&sCb[SWZ(r, c8)] = *(const ushort8*)&xrow[1600 + c8];
    *(ushort8*)&sBb[SWZ(r, c8)] = *(const ushort8*)&xrow[1536 + c8];
  }
  #pragma unroll
  for (int it = 0; it < 16; ++it) {
    int idx = it * 256 + tid;
    int r = idx >> 6, cc = idx & 63;
    sXT[SWZ(cc, r)] = xcb[(trow + r) * CONVD + h * 64 + cc];
  }
  if (tid < 64) {
    float ld = lda_[(trow + tid) * HH + h];
    float dtv = dts[(trow + tid) * HH + h];
    float v = ld;
    #pragma unroll
    for (int o = 1; o < 64; o <<= 1) {
      float u = __shfl_up(v, o, 64);
      if (tid >= o) v += u;
    }
    float tot = __shfl(v, 63, 64);
    clog[tid] = v;
    dt64[tid] = dtv;
    wv64[tid] = dtv * __expf(tot - v);
    cwg[(trow + tid) * HH + h] = __expf(v);
  }
  __syncthreads();

  // dump C tile once per (dir,b,chunk) for the fixup pass
  if (h == 0) {
    ushortT* dst = cbg + ((size_t)((dir * 2 + b) * NCHUNK + c)) * 4096;
    for (int idx = tid; idx < 4096; idx += 256) dst[idx] = sCb[idx];
  }

  int fr = lane & 15, kq = lane >> 4;

  // ---- phase 2: weighted B^T; G = C.B^T; decay -> M(bf16) ----
  #pragma unroll
  for (int it = 0; it < 16; ++it) {
    int idx = it * 256 + tid;
    int s = idx >> 6, n = idx & 63;
    float bv = bf2f(sBb[SWZ(s, n)]) * wv64[s];
    sBT[SWZ(n, s)] = f2bf(bv);
  }
  f32x4 accG[4] = {};
  #pragma unroll
  for (int kt = 0; kt < 2; ++kt) {
    int kk = kt * 32 + kq * 8;
    bf16x8 af = *(const bf16x8*)&sCb[SWZ(w * 16 + fr, kk)];
    #pragma unroll
    for (int j = 0; j < 4; ++j) {
      bf16x8 bf_ = *(const bf16x8*)&sBb[SWZ(j * 16 + fr, kk)];
      accG[j] = __builtin_amdgcn_mfma_f32_16x16x32_bf16(af, bf_, accG[j], 0, 0, 0);
    }
  }
  #pragma unroll
  for (int j = 0; j < 4; ++j) {
    int s = j * 16 + fr;
    float cls = clog[s], dtv = dt64[s];
    #pragma unroll
    for (int r = 0; r < 4; ++r) {
      int t = w * 16 + kq * 4 + r;
      float dec = (s <= t) ? __expf(clog[t] - cls) * dtv : 0.f;
      sMb[SWZ(t, s)] = f2bf(accG[j][r] * dec);
    }
  }
  __syncthreads();

  // ---- phase 3: Y = M.X ; S = wB^T.X (shared X fragments) ----
  f32x4 accY[4] = {}, accS[4] = {};
  #pragma unroll
  for (int kt = 0; kt < 2; ++kt) {
    int kk = kt * 32 + kq * 8;
    bf16x8 aM = *(const bf16x8*)&sMb[SWZ(w * 16 + fr, kk)];
    bf16x8 aB = *(const bf16x8*)&sBT[SWZ(w * 16 + fr, kk)];
    #pragma unroll
    for (int j = 0; j < 4; ++j) {
      bf16x8 bx = *(const bf16x8*)&sXT[SWZ(j * 16 + fr, kk)];
      accY[j] = __builtin_amdgcn_mfma_f32_16x16x32_bf16(aM, bx, accY[j], 0, 0, 0);
      accS[j] = __builtin_amdgcn_mfma_f32_16x16x32_bf16(aB, bx, accS[j], 0, 0, 0);
    }
  }
  ushortT* spb = slocb + ((size_t)gh * NCHUNK + c) * 4096;
  #pragma unroll
  for (int j = 0; j < 4; ++j) {
    #pragma unroll
    for (int r = 0; r < 4; ++r) {
      int t = w * 16 + kq * 4 + r;        // row (t for Y, n for S)
      int p = j * 16 + fr;                // col
      yb[(trow + t) * DI + h * 64 + p] = f2bf(accY[j][r]);
      spb[t * 64 + p] = f2bf(accS[j][r]);
    }
  }
}

// ---------------- pass 2: serial prefix over chunk states (96 blocks) ----------------
__global__ __launch_bounds__(256) void chunk_prefix_kernel(
    const ushortT* __restrict__ slocb, const float* __restrict__ cwg,
    ushortT* __restrict__ sinitb) {
  __shared__ float ldsT[64 * 65];
  int gh = blockIdx.x;
  int dir = gh / 48;
  int rem = gh % 48;
  int b = rem / 24, h = rem % 24;
  int tid = threadIdx.x;
  size_t rowbase = ((size_t)dir * 2 + b) * 1024;
  float R[16];
  #pragma unroll
  for (int j = 0; j < 16; ++j) R[j] = 0.f;
  for (int c = 1; c < NCHUNK; ++c) {
    float W = cwg[(rowbase + (size_t)c * CLEN - 1) * HH + h];
    const ushortT* slot = slocb + ((size_t)gh * NCHUNK + (c - 1)) * 4096;
    #pragma unroll
    for (int j = 0; j < 16; ++j) {
      int idx = j * 256 + tid, n = idx >> 6, p = idx & 63;
      R[j] = __builtin_fmaf(R[j], W, bf2f(slot[idx]));
      ldsT[n * 65 + p] = R[j];
    }
    __syncthreads();
    ushortT* outp = sinitb + ((size_t)gh * (NCHUNK - 1) + (c - 1)) * 4096;
    #pragma unroll
    for (int j = 0; j < 16; ++j) {
      int idx = j * 256 + tid, p = idx >> 6, n = idx & 63;
      outp[SWZ(p, n)] = f2bf(ldsT[n * 65 + p]);
    }
    __syncthreads();
  }
}

// ---------------- pass 3 (MFMA): YI[t,p] = cw[t] * (C_t . S_init) ----------------
__global__ __launch_bounds__(256) void fixup_kernel(
    const ushortT* __restrict__ cbg, const ushortT* __restrict__ sinitb,
    const float* __restrict__ cwg, ushortT* __restrict__ yib) {
  __shared__ ushortT sCb[4096];
  __shared__ ushortT sST[4096];
  int gh = blockIdx.x;
  int c = blockIdx.y + 1;      // 1..15
  int dir = gh / 48;
  int rem = gh % 48;
  int b = rem / 24, h = rem % 24;
  int tid = threadIdx.x, lane = tid & 63, w = tid >> 6;
  size_t rowbase = ((size_t)dir * 2 + b) * 1024;
  size_t trow = rowbase + (size_t)c * CLEN;
  const ushortT* cbSrc = cbg + ((size_t)((dir * 2 + b) * NCHUNK + c)) * 4096;
  const ushortT* stSrc = sinitb + ((size_t)gh * (NCHUNK - 1) + (c - 1)) * 4096;
  #pragma unroll
  for (int ph = 0; ph < 2; ++ph) {
    int base = ph * 2048 + w * 512;
    gload_lds16(cbSrc + base + lane * 8, &sCb[base]);
    gload_lds16(stSrc + base + lane * 8, &sST[base]);
  }
  __syncthreads();
  int fr = lane & 15, kq = lane >> 4;
  f32x4 accY[4] = {};
  #pragma unroll
  for (int kt = 0; kt < 2; ++kt) {
    int kk = kt * 32 + kq * 8;
    bf16x8 aC = *(const bf16x8*)&sCb[SWZ(w * 16 + fr, kk)];
    #pragma unroll
    for (int j = 0; j < 4; ++j) {
      bf16x8 bS = *(const bf16x8*)&sST[SWZ(j * 16 + fr, kk)];
      accY[j] = __builtin_amdgcn_mfma_f32_16x16x32_bf16(aC, bS, accY[j], 0, 0, 0);
    }
  }
  float cwv[4];
  #pragma unroll
  for (int r = 0; r < 4; ++r)
    cwv[r] = cwg[(trow + w * 16 + kq * 4 + r) * HH + h];
  #pragma unroll
  for (int j = 0; j < 4; ++j)
    #pragma unroll
    for (int r = 0; r < 4; ++r) {
      int t = w * 16 + kq * 4 + r, p = j * 16 + fr;
      yib[(trow + t) * DI + h * 64 + p] = f2bf(accY[j][r] * cwv[r]);
    }
}

// ---------------- +D*xs, gate silu(z), RMSNorm, -> bf16 ----------------
__global__ __launch_bounds__(256) void gate_norm_kernel(
    const ushortT* __restrict__ yb, const ushortT* __restrict__ yib,
    const ushortT* __restrict__ zxb, const ushortT* __restrict__ xcb,
    const float* __restrict__ Df, const float* __restrict__ Db,
    const float* __restrict__ nwf, const float* __restrict__ nwb,
    ushortT* __restrict__ yn) {
  __shared__ float lds[4];
  int bid = blockIdx.x;            // 0..4095 (dir*2048 + b*1024 + t)
  int dir = bid >> 11;
  int t = bid & 1023;
  const float* Dp = dir ? Db : Df;
  const float* nw = dir ? nwb : nwf;
  int tid = threadIdx.x;
  bool act = tid < 192;
  int c0 = tid * 8;
  float v[8];
  float ss = 0.f;
  if (act) {
    ushort8 yv8 = *(const ushort8*)&yb[(size_t)bid * DI + c0];
    ushort8 zv8 = *(const ushort8*)&zxb[(size_t)bid * NP1 + c0];
    ushort8 xv8 = *(const ushort8*)&xcb[(size_t)bid * CONVD + c0];
    ushort8 yi8 = {};
    bool hasI = (t >= CLEN);
    if (hasI) yi8 = *(const ushort8*)&yib[(size_t)bid * DI + c0];
    float Dv = Dp[c0 >> 6];
    #pragma unroll
    for (int e = 0; e < 8; ++e) {
      float yv = bf2f(yv8[e]) + (hasI ? bf2f(yi8[e]) : 0.f) + Dv * bf2f(xv8[e]);
      float zv = bf2f(zv8[e]);
      yv *= zv / (1.f + expf(-zv));
      v[e] = yv;
      ss += yv * yv;
    }
  }
  #pragma unroll
  for (int o = 32; o; o >>= 1) ss += __shfl_xor(ss, o, 64);
  if ((tid & 63) == 0) lds[tid >> 6] = ss;
  __syncthreads();
  float ms = (lds[0] + lds[1] + lds[2] + lds[3]) * (1.f / 1536.f);
  float sc = rsqrtf(ms + EPSF);
  if (act) {
    ushort8 o8;
    #pragma unroll
    for (int e = 0; e < 8; ++e) o8[e] = f2bf(v[e] * sc * nw[c0 + e]);
    *(ushort8*)&yn[(size_t)bid * DI + c0] = o8;
  }
}

// ---------------- out[t] = 2x[t] + mf[t] + mb[SEQ[t]] (mf/mb bf16) ----------------
__global__ __launch_bounds__(128) void combine_kernel(const float* __restrict__ x,
    const ushortT* __restrict__ mf, const ushortT* __restrict__ mb,
    float* __restrict__ out) {
  int bid = blockIdx.x;   // b*1024 + t
  int b = bid >> 10, t = bid & 1023;
  int st = seqmap(t);
  int tid = threadIdx.x;
  if (tid >= 96) return;
  int c0 = tid * 8;
  ushort8 fv = *(const ushort8*)&mf[(size_t)bid * DM + c0];
  ushort8 bv = *(const ushort8*)&mb[(size_t)(b * 1024 + st) * DM + c0];
  const float4 x0 = *(const float4*)&x[(size_t)bid * DM + c0];
  const float4 x1 = *(const float4*)&x[(size_t)bid * DM + c0 + 4];
  float4 o0, o1;
  o0.x = 2.f * x0.x + bf2f(fv[0]) + bf2f(bv[0]);
  o0.y = 2.f * x0.y + bf2f(fv[1]) + bf2f(bv[1]);
  o0.z = 2.f * x0.z + bf2f(fv[2]) + bf2f(bv[2]);
  o0.w = 2.f * x0.w + bf2f(fv[3]) + bf2f(bv[3]);
  o1.x = 2.f * x1.x + bf2f(fv[4]) + bf2f(bv[4]);
  o1.y = 2.f * x1.y + bf2f(fv[5]) + bf2f(bv[5]);
  o1.z = 2.f * x1.z + bf2f(fv[6]) + bf2f(bv[6]);
  o1.w = 2.f * x1.w + bf2f(fv[7]) + bf2f(bv[7]);
  *(float4*)&out[(size_t)bid * DM + c0] = o0;
  *(float4*)&out[(size_t)bid * DM + c0 + 4] = o1;
}

extern "C" void kernel_launch(void* const* d_in, const int* in_sizes, int n_in,
                              void* d_out, int out_size, void* d_ws, size_t ws_size,
                              hipStream_t stream) {
  const float* x       = (const float*)d_in[0];
  const float* f_ln_w  = (const float*)d_in[1];
  const float* f_ln_b  = (const float*)d_in[2];
  const float* f_in_w  = (const float*)d_in[3];
  const float* f_cw    = (const float*)d_in[4];
  const float* f_cb    = (const float*)d_in[5];
  const float* f_dtb   = (const float*)d_in[6];
  const float* f_alog  = (const float*)d_in[7];
  const float* f_D     = (const float*)d_in[8];
  const float* f_nw    = (const float*)d_in[9];
  const float* f_ow    = (const float*)d_in[10];
  const float* b_ln_w  = (const float*)d_in[11];
  const float* b_ln_b  = (const float*)d_in[12];
  const float* b_in_w  = (const float*)d_in[13];
  const float* b_cw    = (const float*)d_in[14];
  const float* b_cb    = (const float*)d_in[15];
  const float* b_dtb   = (const float*)d_in[16];
  const float* b_alog  = (const float*)d_in[17];
  const float* b_D     = (const float*)d_in[18];
  const float* b_nw    = (const float*)d_in[19];
  const float* b_ow    = (const float*)d_in[20];

  char* ws = (char*)d_ws;
  size_t off = 0;
  auto carve = [&](size_t bytes) -> char* {
    off = (off + 255) & ~(size_t)255;
    char* p = ws + off;
    off += bytes;
    return p;
  };
  ushortT* XLN   = (ushortT*)carve((size_t)2 * ROWS * DM * 2);
  ushortT* WP1   = (ushortT*)carve((size_t)2 * NP1 * DM * 2);
  ushortT* W2    = (ushortT*)carve((size_t)2 * DM * DI * 2);
  ushortT* ZXB   = (ushortT*)carve((size_t)2 * ROWS * NP1 * 2);
  float*   DTT   = (float*)carve((size_t)2 * ROWS * 128 * 4);
  ushortT* XCB   = (ushortT*)carve((size_t)2 * ROWS * CONVD * 2);
  float*   DTS   = (float*)carve((size_t)2 * ROWS * HH * 4);
  float*   LDA   = (float*)carve((size_t)2 * ROWS * HH * 4);
  ushortT* YB    = (ushortT*)carve((size_t)2 * ROWS * DI * 2);
  ushortT* YIB   = (ushortT*)carve((size_t)2 * ROWS * DI * 2);
  ushortT* YN    = (ushortT*)carve((size_t)2 * ROWS * DI * 2);
  ushortT* MOUTB = (ushortT*)carve((size_t)2 * ROWS * DM * 2);
  ushortT* SLOCB = (ushortT*)carve((size_t)96 * NCHUNK * 4096 * 2);
  ushortT* SINIB = (ushortT*)carve((size_t)96 * (NCHUNK - 1) * 4096 * 2);
  ushortT* CBG   = (ushortT*)carve((size_t)4 * NCHUNK * 4096 * 2);
  float*   CWG   = (float*)carve((size_t)2 * ROWS * HH * 4);

  // weight conversion (merged, vectorized)
  cvt_all_kernel<<<2048, 256, 0, stream>>>(f_in_w, b_in_w, f_ow, b_ow, WP1, W2);

  // layernorm (both dirs)
  ln_kernel<<<4096, 256, 0, stream>>>(x, f_ln_w, f_ln_b, b_ln_w, b_ln_b, XLN);

  // in_proj: [2048,768] x [3328,768]^T -> bf16 z/xBC + f32 dt tail
  gemm_bf16<1><<<dim3(NP1 / 128, ROWS / 128, 2), 256, 0, stream>>>(
      XLN, WP1, DTT, ZXB, DM, DM, DM, NP1,
      (long)ROWS * DM, (long)NP1 * DM, (long)ROWS * 128, (long)ROWS * NP1);

  // conv + dt/logdA
  conv_dt_kernel<<<4096, 256, 0, stream>>>(ZXB, DTT, f_cw, f_cb, b_cw, b_cb,
                                           f_dtb, f_alog, b_dtb, b_alog,
                                           XCB, DTS, LDA);

  // chunked scan: pass 1 (SSD/MFMA), pass 2 (prefix), pass 3 (MFMA fixup)
  ssd_chunk_kernel<<<dim3(96, NCHUNK), 256, 0, stream>>>(XCB, DTS, LDA, YB, SLOCB, CWG, CBG);
  chunk_prefix_kernel<<<96, 256, 0, stream>>>(SLOCB, CWG, SINIB);
  fixup_kernel<<<dim3(96, NCHUNK - 1), 256, 0, stream>>>(CBG, SINIB, CWG, YIB);

  // gate + rmsnorm
  gate_norm_kernel<<<4096, 256, 0, stream>>>(YB, YIB, ZXB, XCB, f_D, b_D, f_nw, b_nw, YN);

  // out_proj: [2048,1536] x [768,1536]^T -> [2048,768] bf16
  gemm_bf16<0><<<dim3(DM / 128, ROWS / 128, 2), 256, 0, stream>>>(
      YN, W2, nullptr, MOUTB, DI, DI, DI, DM,
      (long)ROWS * DI, (long)DM * DI, 0, (long)ROWS * DM);

  // combine
  combine_kernel<<<2048, 128, 0, stream>>>(x, MOUTB, MOUTB + (size_t)ROWS * DM, (float*)d_out);
}